// Round 4
// baseline (1558.822 us; speedup 1.0000x reference)
//
#include <hip/hip_runtime.h>

typedef unsigned short u16;
typedef __attribute__((ext_vector_type(8))) short bf16x8;
typedef __attribute__((ext_vector_type(4))) float f32x4;

// Problem dims
#define M_ROWS 100352   // 512 * 196
#define NB     512
#define NTOK   196
#define CDIM   256
#define NHEADS 8
#define HDIM   32
#define ANUM   49
#define CB     64       // batch chunk for kv
#define NCHUNK 8

__device__ __forceinline__ u16 f2bf(float f) {
    union { float f; unsigned u; } c; c.f = f;
    return (u16)((c.u + 0x7FFFu + ((c.u >> 16) & 1u)) >> 16);
}
__device__ __forceinline__ float bf2f(u16 u) {
    union { unsigned u; float f; } c; c.u = ((unsigned)u) << 16;
    return c.f;
}

// ---------------------------------------------------------------------------
// Cast the three weight matrices to bf16. 65,536 threads x 4 elems.
// ---------------------------------------------------------------------------
__global__ __launch_bounds__(256)
void cast_w(const float* __restrict__ wq, const float* __restrict__ wkv,
            const float* __restrict__ wproj,
            u16* __restrict__ wqb, u16* __restrict__ wkvb, u16* __restrict__ wprojb)
{
    const int idx4 = blockIdx.x * 256 + threadIdx.x;   // 0..65535
    const float* src; u16* dst; int off;
    if (idx4 < 16384)      { src = wq;    dst = wqb;    off = idx4; }
    else if (idx4 < 49152) { src = wkv;   dst = wkvb;   off = idx4 - 16384; }
    else                   { src = wproj; dst = wprojb; off = idx4 - 49152; }
    float4 v = *reinterpret_cast<const float4*>(&src[(size_t)off * 4]);
    ushort4 o;
    o.x = f2bf(v.x); o.y = f2bf(v.y); o.z = f2bf(v.z); o.w = f2bf(v.w);
    *reinterpret_cast<ushort4*>(&dst[(size_t)off * 4]) = o;
}

// ---------------------------------------------------------------------------
// MFMA GEMM, A fp32 (converted inline), B bf16 [n][256], C bf16.
// C[m][n] = sum_k A[m][k]*Bw[n][k].  Tile 128x128, BK=32, 4 waves (2x2),
// each wave 64x64 via 4x4 frags of mfma_f32_16x16x32_bf16.
// ---------------------------------------------------------------------------
__global__ __launch_bounds__(256)
void gemm_f32a(const float* __restrict__ A, const u16* __restrict__ Bw,
               u16* __restrict__ C, int ldc)
{
    __shared__ u16 As[128 * 32];
    __shared__ u16 Bs[128 * 32];

    const int tid  = threadIdx.x;
    const int lane = tid & 63, wid = tid >> 6;
    const int wm = wid >> 1, wn = wid & 1;
    const int row0 = blockIdx.x * 128;
    const int col0 = blockIdx.y * 128;

    f32x4 acc[4][4] = {};
    const int lrow = lane & 15;
    const int lk   = (lane >> 4) * 8;

    for (int k0 = 0; k0 < 256; k0 += 32) {
        #pragma unroll
        for (int i = 0; i < 2; ++i) {
            const int c = tid + i * 256;           // 0..511
            const int r = c >> 2, kc = c & 3;
            const float* ap = &A[(size_t)(row0 + r) * 256 + k0 + kc * 8];
            float4 a0 = *reinterpret_cast<const float4*>(ap);
            float4 a1 = *reinterpret_cast<const float4*>(ap + 4);
            bf16x8 t;
            t[0] = (short)f2bf(a0.x); t[1] = (short)f2bf(a0.y);
            t[2] = (short)f2bf(a0.z); t[3] = (short)f2bf(a0.w);
            t[4] = (short)f2bf(a1.x); t[5] = (short)f2bf(a1.y);
            t[6] = (short)f2bf(a1.z); t[7] = (short)f2bf(a1.w);
            *reinterpret_cast<bf16x8*>(&As[r * 32 + kc * 8]) = t;
            bf16x8 vb = *reinterpret_cast<const bf16x8*>(
                &Bw[(size_t)(col0 + r) * 256 + k0 + kc * 8]);
            *reinterpret_cast<bf16x8*>(&Bs[r * 32 + kc * 8]) = vb;
        }
        __syncthreads();

        bf16x8 af[4], bfr[4];
        #pragma unroll
        for (int m = 0; m < 4; ++m)
            af[m] = *reinterpret_cast<bf16x8*>(&As[(wm*64 + m*16 + lrow) * 32 + lk]);
        #pragma unroll
        for (int n = 0; n < 4; ++n)
            bfr[n] = *reinterpret_cast<bf16x8*>(&Bs[(wn*64 + n*16 + lrow) * 32 + lk]);
        #pragma unroll
        for (int m = 0; m < 4; ++m)
            #pragma unroll
            for (int n = 0; n < 4; ++n)
                acc[m][n] = __builtin_amdgcn_mfma_f32_16x16x32_bf16(
                                af[m], bfr[n], acc[m][n], 0, 0, 0);
        __syncthreads();
    }

    // C/D layout: col = lane&15, row = (lane>>4)*4 + r
    #pragma unroll
    for (int n = 0; n < 4; ++n) {
        const int ccol = col0 + wn*64 + n*16 + (lane & 15);
        #pragma unroll
        for (int m = 0; m < 4; ++m) {
            const int rbase = row0 + wm*64 + m*16 + (lane >> 4) * 4;
            #pragma unroll
            for (int r = 0; r < 4; ++r)
                C[(size_t)(rbase + r) * ldc + ccol] = f2bf(acc[m][n][r]);
        }
    }
}

// ---------------------------------------------------------------------------
// MFMA GEMM, A bf16, C fp32 + bias.  Same tiling.
// ---------------------------------------------------------------------------
__global__ __launch_bounds__(256)
void gemm_bf16a(const u16* __restrict__ A, const u16* __restrict__ Bw,
                const float* __restrict__ bias, float* __restrict__ C, int ldc)
{
    __shared__ u16 As[128 * 32];
    __shared__ u16 Bs[128 * 32];

    const int tid  = threadIdx.x;
    const int lane = tid & 63, wid = tid >> 6;
    const int wm = wid >> 1, wn = wid & 1;
    const int row0 = blockIdx.x * 128;
    const int col0 = blockIdx.y * 128;

    f32x4 acc[4][4] = {};
    const int lrow = lane & 15;
    const int lk   = (lane >> 4) * 8;

    for (int k0 = 0; k0 < 256; k0 += 32) {
        #pragma unroll
        for (int i = 0; i < 2; ++i) {
            const int c = tid + i * 256;
            const int r = c >> 2, kc = c & 3;
            bf16x8 va = *reinterpret_cast<const bf16x8*>(
                &A[(size_t)(row0 + r) * 256 + k0 + kc * 8]);
            *reinterpret_cast<bf16x8*>(&As[r * 32 + kc * 8]) = va;
            bf16x8 vb = *reinterpret_cast<const bf16x8*>(
                &Bw[(size_t)(col0 + r) * 256 + k0 + kc * 8]);
            *reinterpret_cast<bf16x8*>(&Bs[r * 32 + kc * 8]) = vb;
        }
        __syncthreads();

        bf16x8 af[4], bfr[4];
        #pragma unroll
        for (int m = 0; m < 4; ++m)
            af[m] = *reinterpret_cast<bf16x8*>(&As[(wm*64 + m*16 + lrow) * 32 + lk]);
        #pragma unroll
        for (int n = 0; n < 4; ++n)
            bfr[n] = *reinterpret_cast<bf16x8*>(&Bs[(wn*64 + n*16 + lrow) * 32 + lk]);
        #pragma unroll
        for (int m = 0; m < 4; ++m)
            #pragma unroll
            for (int n = 0; n < 4; ++n)
                acc[m][n] = __builtin_amdgcn_mfma_f32_16x16x32_bf16(
                                af[m], bfr[n], acc[m][n], 0, 0, 0);
        __syncthreads();
    }

    #pragma unroll
    for (int n = 0; n < 4; ++n) {
        const int ccol = col0 + wn*64 + n*16 + (lane & 15);
        const float bv = bias[ccol];
        #pragma unroll
        for (int m = 0; m < 4; ++m) {
            const int rbase = row0 + wm*64 + m*16 + (lane >> 4) * 4;
            #pragma unroll
            for (int r = 0; r < 4; ++r)
                C[(size_t)(rbase + r) * ldc + ccol] = acc[m][n][r] + bv;
        }
    }
}

// ---------------------------------------------------------------------------
// Agent pooling over bf16 q: agent[b][a][ch] = mean of 2x2 block.
// ---------------------------------------------------------------------------
__global__ __launch_bounds__(256)
void pool_kernel(const u16* __restrict__ qb, u16* __restrict__ agentb)
{
    const int idx = blockIdx.x * 256 + threadIdx.x;   // 512*49*256 exact
    const int ch = idx & 255;
    const int a  = (idx >> 8) % ANUM;
    const int b  = idx / (ANUM * CDIM);
    const int p1 = a / 7, p2 = a % 7;
    const u16* q0 = qb + (size_t)b * NTOK * CDIM;
    float s = 0.f;
    #pragma unroll
    for (int i2 = 0; i2 < 2; ++i2)
        #pragma unroll
        for (int j2 = 0; j2 < 2; ++j2) {
            const int n = (p1*2 + i2) * 14 + (p2*2 + j2);
            s += bf2f(q0[(size_t)n * CDIM + ch]);
        }
    agentb[idx] = f2bf(0.25f * s);
}

// ---------------------------------------------------------------------------
// Stage A per (b,h): agent_v = softmax_n(scale * agent_h K_h^T) @ V_h
// kvb: chunk-local [CB*196][512] bf16 (k at h*32, v at 256+h*32).
// ---------------------------------------------------------------------------
__global__ __launch_bounds__(256)
void attn_agent(const u16* __restrict__ kvb, const u16* __restrict__ agentb,
                u16* __restrict__ agentvb, int base_b)
{
    __shared__ float ah[ANUM][33];
    __shared__ float kh[NTOK][33];
    __shared__ float vh[NTOK][33];
    __shared__ float pbuf[NTOK];
    __shared__ float red[16];
    __shared__ float accs[8][32];

    const int bid = blockIdx.x;
    const int bl = bid >> 3, h = bid & 7;
    const int b = base_b + bl;
    const int tid = threadIdx.x;
    const float scale = 0.1767766952966369f;   // 32^-0.5

    const u16* agb = agentb + (size_t)b * ANUM * CDIM + h * HDIM;
    for (int i = tid; i < ANUM * 4; i += 256) {
        const int a = i >> 2, kc = i & 3;
        bf16x8 v = *reinterpret_cast<const bf16x8*>(&agb[(size_t)a * CDIM + kc*8]);
        #pragma unroll
        for (int j = 0; j < 8; ++j) ah[a][kc*8 + j] = bf2f((u16)v[j]);
    }
    const u16* kb = kvb + (size_t)bl * NTOK * 512 + h * HDIM;
    const u16* vb = kb + 256;
    for (int i = tid; i < NTOK * 4; i += 256) {
        const int n = i >> 2, kc = i & 3;
        bf16x8 v = *reinterpret_cast<const bf16x8*>(&kb[(size_t)n * 512 + kc*8]);
        #pragma unroll
        for (int j = 0; j < 8; ++j) kh[n][kc*8 + j] = bf2f((u16)v[j]);
        bf16x8 w = *reinterpret_cast<const bf16x8*>(&vb[(size_t)n * 512 + kc*8]);
        #pragma unroll
        for (int j = 0; j < 8; ++j) vh[n][kc*8 + j] = bf2f((u16)w[j]);
    }
    __syncthreads();

    const int lane = tid & 63, wid = tid >> 6;
    u16* avout = agentvb + ((size_t)b * NHEADS + h) * ANUM * HDIM;

    for (int a = 0; a < ANUM; ++a) {
        float s = -1e30f;
        if (tid < NTOK) {
            float d = 0.f;
            #pragma unroll
            for (int kk = 0; kk < HDIM; ++kk) d += ah[a][kk] * kh[tid][kk];
            s = d * scale;
        }
        float m = s;
        #pragma unroll
        for (int o = 32; o > 0; o >>= 1) m = fmaxf(m, __shfl_down(m, o));
        if (lane == 0) red[wid] = m;
        __syncthreads();
        const float mx = fmaxf(fmaxf(red[0], red[1]), fmaxf(red[2], red[3]));
        float p = (tid < NTOK) ? __expf(s - mx) : 0.f;
        float su = p;
        #pragma unroll
        for (int o = 32; o > 0; o >>= 1) su += __shfl_down(su, o);
        if (lane == 0) red[8 + wid] = su;
        if (tid < NTOK) pbuf[tid] = p;
        __syncthreads();
        const float inv = 1.f / (red[8] + red[9] + red[10] + red[11]);
        const int dd = tid & 31, chunk = tid >> 5;
        const int n0 = chunk * 25, n1 = min(n0 + 25, NTOK);
        float part = 0.f;
        for (int nn = n0; nn < n1; ++nn) part += pbuf[nn] * vh[nn][dd];
        accs[chunk][dd] = part;
        __syncthreads();
        if (tid < 32) {
            float t = 0.f;
            #pragma unroll
            for (int cc = 0; cc < 8; ++cc) t += accs[cc][tid];
            avout[a * HDIM + tid] = f2bf(t * inv);
        }
        __syncthreads();
    }
}

// ---------------------------------------------------------------------------
// Stage B per (b,h): out = softmax_a(scale * Q_h agent_h^T) @ agent_v
// Reads q slice from qb (bf16) and overwrites the SAME slice with the
// attention output (each thread reads exactly what it writes -> safe).
// ---------------------------------------------------------------------------
__global__ __launch_bounds__(256)
void attn_q(u16* __restrict__ qb, const u16* __restrict__ agentb,
            const u16* __restrict__ agentvb)
{
    __shared__ float ah[ANUM][33];
    __shared__ float av[ANUM][33];

    const int bh = blockIdx.x;
    const int b = bh >> 3, h = bh & 7;
    const int tid = threadIdx.x;
    const float scale = 0.1767766952966369f;

    const u16* agb = agentb + (size_t)b * ANUM * CDIM + h * HDIM;
    const u16* avb = agentvb + (size_t)bh * ANUM * HDIM;
    for (int i = tid; i < ANUM * 4; i += 256) {
        const int a = i >> 2, kc = i & 3;
        bf16x8 v = *reinterpret_cast<const bf16x8*>(&agb[(size_t)a * CDIM + kc*8]);
        #pragma unroll
        for (int j = 0; j < 8; ++j) ah[a][kc*8 + j] = bf2f((u16)v[j]);
        bf16x8 w = *reinterpret_cast<const bf16x8*>(&avb[a * HDIM + kc*8]);
        #pragma unroll
        for (int j = 0; j < 8; ++j) av[a][kc*8 + j] = bf2f((u16)w[j]);
    }
    __syncthreads();

    const int n = tid;
    if (n >= NTOK) return;

    u16* qrow = qb + ((size_t)b * NTOK + n) * CDIM + h * HDIM;
    float qr[HDIM];
    #pragma unroll
    for (int kc = 0; kc < 4; ++kc) {
        bf16x8 v = *reinterpret_cast<const bf16x8*>(&qrow[kc*8]);
        #pragma unroll
        for (int j = 0; j < 8; ++j) qr[kc*8 + j] = bf2f((u16)v[j]);
    }

    float s[ANUM];
    float mx = -1e30f;
    for (int a = 0; a < ANUM; ++a) {
        float d = 0.f;
        #pragma unroll
        for (int kk = 0; kk < HDIM; ++kk) d += qr[kk] * ah[a][kk];
        s[a] = d * scale;
        mx = fmaxf(mx, s[a]);
    }
    float sum = 0.f;
    for (int a = 0; a < ANUM; ++a) { s[a] = __expf(s[a] - mx); sum += s[a]; }
    const float inv = 1.f / sum;

    float o[HDIM];
    #pragma unroll
    for (int kk = 0; kk < HDIM; ++kk) o[kk] = 0.f;
    for (int a = 0; a < ANUM; ++a) {
        const float p = s[a];
        #pragma unroll
        for (int kk = 0; kk < HDIM; ++kk) o[kk] += p * av[a][kk];
    }

    #pragma unroll
    for (int kc = 0; kc < 4; ++kc) {
        bf16x8 t;
        #pragma unroll
        for (int j = 0; j < 8; ++j) t[j] = (short)f2bf(o[kc*8 + j] * inv);
        *reinterpret_cast<bf16x8*>(&qrow[kc*8]) = t;
    }
}

// ---------------------------------------------------------------------------
extern "C" void kernel_launch(void* const* d_in, const int* in_sizes, int n_in,
                              void* d_out, int out_size, void* d_ws, size_t ws_size,
                              hipStream_t stream)
{
    const float* x     = (const float*)d_in[0];
    const float* wq    = (const float*)d_in[1];
    const float* wkv   = (const float*)d_in[2];
    const float* wproj = (const float*)d_in[3];
    const float* bproj = (const float*)d_in[4];
    float* out = (float*)d_out;

    // workspace (u16 elements), total 45,197,312 u16 = 90.4 MB
    u16* wqb     = (u16*)d_ws;                       //     65,536
    u16* wkvb    = wqb    + 65536;                   //    131,072
    u16* wprojb  = wkvb   + 131072;                  //     65,536
    u16* qb      = wprojb + 65536;                   // 25,690,112  (q, then attn-out, in place)
    u16* agentb  = qb     + (size_t)M_ROWS * CDIM;   //  6,422,528
    u16* agentvb = agentb + (size_t)NB*ANUM*CDIM;    //  6,422,528
    u16* kvb     = agentvb + (size_t)NB*NHEADS*ANUM*HDIM; // 6,422,528 (chunk-reused)

    const dim3 blk(256);

    // 0) weights -> bf16
    cast_w<<<dim3(256), blk, 0, stream>>>(wq, wkv, wproj, wqb, wkvb, wprojb);
    // 1) q = x @ wq^T  (bf16 out)
    gemm_f32a<<<dim3(M_ROWS/128, 2), blk, 0, stream>>>(x, wqb, qb, 256);
    // 2) agent pooling
    pool_kernel<<<dim3((NB*ANUM*CDIM)/256), blk, 0, stream>>>(qb, agentb);
    // 3) per-chunk: kv GEMM + agent attention (kvb reused; stream serializes)
    for (int ch = 0; ch < NCHUNK; ++ch) {
        const float* xch = x + (size_t)ch * CB * NTOK * CDIM;
        gemm_f32a<<<dim3((CB*NTOK)/128, 4), blk, 0, stream>>>(xch, wkvb, kvb, 512);
        attn_agent<<<dim3(CB*NHEADS), blk, 0, stream>>>(kvb, agentb, agentvb, ch*CB);
    }
    // 4) q attention (in-place into qb)
    attn_q<<<dim3(NB*NHEADS), blk, 0, stream>>>(qb, agentb, agentvb);
    // 5) out = attn @ wproj^T + bias (fp32 out)
    gemm_bf16a<<<dim3(M_ROWS/128, 2), blk, 0, stream>>>(qb, wprojb, bproj, out, 256);
}

// Round 6
// 530.128 us; speedup vs baseline: 2.9405x; 2.9405x over previous
//
#include <hip/hip_runtime.h>

typedef unsigned short u16;
typedef __attribute__((ext_vector_type(8))) short bf16x8;
typedef __attribute__((ext_vector_type(4))) float f32x4;

// Problem dims
#define M_ROWS 100352   // 512 * 196
#define NB     512
#define NTOK   196
#define CDIM   256
#define NHEADS 8
#define HDIM   32
#define ANUM   49
#define CB     128      // batch chunk for kv
#define NCHUNK 4

__device__ __forceinline__ u16 f2bf(float f) {
    union { float f; unsigned u; } c; c.f = f;
    return (u16)((c.u + 0x7FFFu + ((c.u >> 16) & 1u)) >> 16);
}
__device__ __forceinline__ float bf2f(u16 u) {
    union { unsigned u; float f; } c; c.u = ((unsigned)u) << 16;
    return c.f;
}

// ---------------------------------------------------------------------------
// Cast the three weight matrices to bf16.
// ---------------------------------------------------------------------------
__global__ __launch_bounds__(256)
void cast_w(const float* __restrict__ wq, const float* __restrict__ wkv,
            const float* __restrict__ wproj,
            u16* __restrict__ wqb, u16* __restrict__ wkvb, u16* __restrict__ wprojb)
{
    const int idx4 = blockIdx.x * 256 + threadIdx.x;   // 0..65535
    const float* src; u16* dst; int off;
    if (idx4 < 16384)      { src = wq;    dst = wqb;    off = idx4; }
    else if (idx4 < 49152) { src = wkv;   dst = wkvb;   off = idx4 - 16384; }
    else                   { src = wproj; dst = wprojb; off = idx4 - 49152; }
    float4 v = *reinterpret_cast<const float4*>(&src[(size_t)off * 4]);
    ushort4 o;
    o.x = f2bf(v.x); o.y = f2bf(v.y); o.z = f2bf(v.z); o.w = f2bf(v.w);
    *reinterpret_cast<ushort4*>(&dst[(size_t)off * 4]) = o;
}

// ---------------------------------------------------------------------------
// MFMA GEMM, A fp32 (converted inline), B bf16 [n][256], C bf16.
// Tile 128x128, BK=32, 4 waves (2x2), each wave 64x64.
// ---------------------------------------------------------------------------
__global__ __launch_bounds__(256)
void gemm_f32a(const float* __restrict__ A, const u16* __restrict__ Bw,
               u16* __restrict__ C, int ldc)
{
    __shared__ u16 As[128 * 32];
    __shared__ u16 Bs[128 * 32];

    const int tid  = threadIdx.x;
    const int lane = tid & 63, wid = tid >> 6;
    const int wm = wid >> 1, wn = wid & 1;
    const int row0 = blockIdx.x * 128;
    const int col0 = blockIdx.y * 128;

    f32x4 acc[4][4] = {};
    const int lrow = lane & 15;
    const int lk   = (lane >> 4) * 8;

    for (int k0 = 0; k0 < 256; k0 += 32) {
        #pragma unroll
        for (int i = 0; i < 2; ++i) {
            const int c = tid + i * 256;
            const int r = c >> 2, kc = c & 3;
            const float* ap = &A[(size_t)(row0 + r) * 256 + k0 + kc * 8];
            float4 a0 = *reinterpret_cast<const float4*>(ap);
            float4 a1 = *reinterpret_cast<const float4*>(ap + 4);
            bf16x8 t;
            t[0] = (short)f2bf(a0.x); t[1] = (short)f2bf(a0.y);
            t[2] = (short)f2bf(a0.z); t[3] = (short)f2bf(a0.w);
            t[4] = (short)f2bf(a1.x); t[5] = (short)f2bf(a1.y);
            t[6] = (short)f2bf(a1.z); t[7] = (short)f2bf(a1.w);
            *reinterpret_cast<bf16x8*>(&As[r * 32 + kc * 8]) = t;
            bf16x8 vb = *reinterpret_cast<const bf16x8*>(
                &Bw[(size_t)(col0 + r) * 256 + k0 + kc * 8]);
            *reinterpret_cast<bf16x8*>(&Bs[r * 32 + kc * 8]) = vb;
        }
        __syncthreads();

        bf16x8 af[4], bfr[4];
        #pragma unroll
        for (int m = 0; m < 4; ++m)
            af[m] = *reinterpret_cast<bf16x8*>(&As[(wm*64 + m*16 + lrow) * 32 + lk]);
        #pragma unroll
        for (int n = 0; n < 4; ++n)
            bfr[n] = *reinterpret_cast<bf16x8*>(&Bs[(wn*64 + n*16 + lrow) * 32 + lk]);
        #pragma unroll
        for (int m = 0; m < 4; ++m)
            #pragma unroll
            for (int n = 0; n < 4; ++n)
                acc[m][n] = __builtin_amdgcn_mfma_f32_16x16x32_bf16(
                                af[m], bfr[n], acc[m][n], 0, 0, 0);
        __syncthreads();
    }

    #pragma unroll
    for (int n = 0; n < 4; ++n) {
        const int ccol = col0 + wn*64 + n*16 + (lane & 15);
        #pragma unroll
        for (int m = 0; m < 4; ++m) {
            const int rbase = row0 + wm*64 + m*16 + (lane >> 4) * 4;
            #pragma unroll
            for (int r = 0; r < 4; ++r)
                C[(size_t)(rbase + r) * ldc + ccol] = f2bf(acc[m][n][r]);
        }
    }
}

// ---------------------------------------------------------------------------
// MFMA GEMM, A bf16, C fp32 + bias.
// ---------------------------------------------------------------------------
__global__ __launch_bounds__(256)
void gemm_bf16a(const u16* __restrict__ A, const u16* __restrict__ Bw,
                const float* __restrict__ bias, float* __restrict__ C, int ldc)
{
    __shared__ u16 As[128 * 32];
    __shared__ u16 Bs[128 * 32];

    const int tid  = threadIdx.x;
    const int lane = tid & 63, wid = tid >> 6;
    const int wm = wid >> 1, wn = wid & 1;
    const int row0 = blockIdx.x * 128;
    const int col0 = blockIdx.y * 128;

    f32x4 acc[4][4] = {};
    const int lrow = lane & 15;
    const int lk   = (lane >> 4) * 8;

    for (int k0 = 0; k0 < 256; k0 += 32) {
        #pragma unroll
        for (int i = 0; i < 2; ++i) {
            const int c = tid + i * 256;
            const int r = c >> 2, kc = c & 3;
            bf16x8 va = *reinterpret_cast<const bf16x8*>(
                &A[(size_t)(row0 + r) * 256 + k0 + kc * 8]);
            *reinterpret_cast<bf16x8*>(&As[r * 32 + kc * 8]) = va;
            bf16x8 vb = *reinterpret_cast<const bf16x8*>(
                &Bw[(size_t)(col0 + r) * 256 + k0 + kc * 8]);
            *reinterpret_cast<bf16x8*>(&Bs[r * 32 + kc * 8]) = vb;
        }
        __syncthreads();

        bf16x8 af[4], bfr[4];
        #pragma unroll
        for (int m = 0; m < 4; ++m)
            af[m] = *reinterpret_cast<bf16x8*>(&As[(wm*64 + m*16 + lrow) * 32 + lk]);
        #pragma unroll
        for (int n = 0; n < 4; ++n)
            bfr[n] = *reinterpret_cast<bf16x8*>(&Bs[(wn*64 + n*16 + lrow) * 32 + lk]);
        #pragma unroll
        for (int m = 0; m < 4; ++m)
            #pragma unroll
            for (int n = 0; n < 4; ++n)
                acc[m][n] = __builtin_amdgcn_mfma_f32_16x16x32_bf16(
                                af[m], bfr[n], acc[m][n], 0, 0, 0);
        __syncthreads();
    }

    #pragma unroll
    for (int n = 0; n < 4; ++n) {
        const int ccol = col0 + wn*64 + n*16 + (lane & 15);
        const float bv = bias[ccol];
        #pragma unroll
        for (int m = 0; m < 4; ++m) {
            const int rbase = row0 + wm*64 + m*16 + (lane >> 4) * 4;
            #pragma unroll
            for (int r = 0; r < 4; ++r)
                C[(size_t)(rbase + r) * ldc + ccol] = acc[m][n][r] + bv;
        }
    }
}

// ---------------------------------------------------------------------------
// Agent pooling over bf16 q: agent[b][a][ch] = mean of 2x2 block.
// ---------------------------------------------------------------------------
__global__ __launch_bounds__(256)
void pool_kernel(const u16* __restrict__ qb, u16* __restrict__ agentb)
{
    const int idx = blockIdx.x * 256 + threadIdx.x;
    const int ch = idx & 255;
    const int a  = (idx >> 8) % ANUM;
    const int b  = idx / (ANUM * CDIM);
    const int p1 = a / 7, p2 = a % 7;
    const u16* q0 = qb + (size_t)b * NTOK * CDIM;
    float s = 0.f;
    #pragma unroll
    for (int i2 = 0; i2 < 2; ++i2)
        #pragma unroll
        for (int j2 = 0; j2 < 2; ++j2) {
            const int n = (p1*2 + i2) * 14 + (p2*2 + j2);
            s += bf2f(q0[(size_t)n * CDIM + ch]);
        }
    agentb[idx] = f2bf(0.25f * s);
}

// ---------------------------------------------------------------------------
// Fused agent attention per (b,h): all 4 einsums via MFMA 16x16x32 (K=32=HDIM).
//   S1 = (A*scale)·K^T  -> softmax_n -> P1 ; AV = P1·V   (stored transposed)
//   S2 = Q·(A*scale)^T  -> softmax_a -> P2 ; O  = P2·AV  -> qb in place
// 256 threads = 4 waves; wave w owns agent-tile w in phase 1 and token-tiles
// {w, w+4, w+8(, 12 for w=0)} in phases 2-3.  C/D layout per m89:
// row = (lane>>4)*4+r, col = lane&15.
// LDS: padded strides (40/232/72 u16) keep bank aliasing <= 2-way (free).
// sP2 aliases the dead sK+sVt region after phase 1b.
// ---------------------------------------------------------------------------
#define SA_LD   40
#define SK_LD   40
#define SVT_LD  232
#define SP1_LD  232
#define SAVT_LD 72
#define SP2_LD  72
#define OFF_A   0
#define OFF_K   2560     // 64*40
#define OFF_VT  10880    // OFF_K + 208*40
#define OFF_P2  2560     // alias over sK+sVt (ends 17536 < OFF_P1)
#define OFF_P1  18304    // OFF_VT + 32*232
#define OFF_AVT 33152    // OFF_P1 + 64*232
#define LDS_U16 35456    // OFF_AVT + 32*72 (= 70,912 B)

__global__ __launch_bounds__(256)
void fused_attn(const u16* __restrict__ kvb, const u16* __restrict__ agentb,
                u16* __restrict__ qb, int base_b)
{
    __shared__ __align__(16) u16 lds[LDS_U16];
    const int tid  = threadIdx.x;
    const int lane = tid & 63, w = tid >> 6;
    const int li = lane & 15, g = lane >> 4;
    const int bl = blockIdx.x >> 3, h = blockIdx.x & 7;
    const int b  = base_b + bl;
    const float scale = 0.1767766952966369f;   // 32^-0.5
    const f32x4 z = {0.f, 0.f, 0.f, 0.f};

    // zero all of LDS (pad rows/cols must be 0)
    for (int i = tid; i < LDS_U16 / 8; i += 256)
        *reinterpret_cast<f32x4*>(&lds[i * 8]) = z;
    __syncthreads();

    // ---- stage sA (pre-scaled), sK, sVt (transposed) ----
    {
        const int a = tid >> 2, kc = tid & 3;
        if (a < ANUM) {
            bf16x8 v = *reinterpret_cast<const bf16x8*>(
                &agentb[((size_t)b * ANUM + a) * CDIM + h * HDIM + kc * 8]);
            bf16x8 t;
            #pragma unroll
            for (int j2 = 0; j2 < 8; ++j2)
                t[j2] = (short)f2bf(bf2f((u16)v[j2]) * scale);
            *reinterpret_cast<bf16x8*>(&lds[OFF_A + a * SA_LD + kc * 8]) = t;
        }
    }
    for (int i = tid; i < NTOK * 4; i += 256) {
        const int n = i >> 2, kc = i & 3;
        bf16x8 v = *reinterpret_cast<const bf16x8*>(
            &kvb[((size_t)(bl * NTOK + n)) * 512 + h * HDIM + kc * 8]);
        *reinterpret_cast<bf16x8*>(&lds[OFF_K + n * SK_LD + kc * 8]) = v;
    }
    for (int i = tid; i < NTOK * 2; i += 256) {
        const int n = i >> 1, dh = i & 1;
        const u16* src = &kvb[((size_t)(bl * NTOK + n)) * 512 + 256 + h * HDIM + dh * 16];
        bf16x8 v0 = *reinterpret_cast<const bf16x8*>(src);
        bf16x8 v1 = *reinterpret_cast<const bf16x8*>(src + 8);
        #pragma unroll
        for (int j2 = 0; j2 < 8; ++j2) {
            lds[OFF_VT + (dh * 16 + j2) * SVT_LD + n]     = (u16)v0[j2];
            lds[OFF_VT + (dh * 16 + 8 + j2) * SVT_LD + n] = (u16)v1[j2];
        }
    }
    __syncthreads();

    // ---- Phase 1: S1 = A·K^T (agent-tile w), softmax over 196 tokens ----
    {
        bf16x8 af = *reinterpret_cast<bf16x8*>(&lds[OFF_A + (w*16 + li) * SA_LD + g*8]);
        f32x4 c[13];
        #pragma unroll
        for (int j = 0; j < 13; ++j) {
            bf16x8 kf = *reinterpret_cast<bf16x8*>(&lds[OFF_K + (j*16 + li) * SK_LD + g*8]);
            c[j] = __builtin_amdgcn_mfma_f32_16x16x32_bf16(af, kf, z, 0, 0, 0);
        }
        #pragma unroll
        for (int r = 0; r < 4; ++r) {
            float m = -1e30f;
            #pragma unroll
            for (int j = 0; j < 13; ++j)
                if (j < 12 || li < 4) m = fmaxf(m, c[j][r]);   // col j*16+li < 196
            #pragma unroll
            for (int d = 1; d < 16; d <<= 1) m = fmaxf(m, __shfl_xor(m, d));
            float p[13]; float su = 0.f;
            #pragma unroll
            for (int j = 0; j < 13; ++j) {
                p[j] = (j < 12 || li < 4) ? __expf(c[j][r] - m) : 0.f;
                su += p[j];
            }
            #pragma unroll
            for (int d = 1; d < 16; d <<= 1) su += __shfl_xor(su, d);
            const float inv = 1.f / su;
            const int arow = w*16 + g*4 + r;
            #pragma unroll
            for (int j = 0; j < 13; ++j)
                lds[OFF_P1 + arow * SP1_LD + j*16 + li] = f2bf(p[j] * inv);
        }
    }
    __syncthreads();

    // ---- Phase 1b: AV = P1·V (K=224 over tokens), store AV^T ----
    #pragma unroll
    for (int dt = 0; dt < 2; ++dt) {
        f32x4 acc = z;
        #pragma unroll
        for (int kk = 0; kk < 7; ++kk) {
            bf16x8 pa = *reinterpret_cast<bf16x8*>(
                &lds[OFF_P1 + (w*16 + li) * SP1_LD + kk*32 + g*8]);
            bf16x8 vb = *reinterpret_cast<bf16x8*>(
                &lds[OFF_VT + (dt*16 + li) * SVT_LD + kk*32 + g*8]);
            acc = __builtin_amdgcn_mfma_f32_16x16x32_bf16(pa, vb, acc, 0, 0, 0);
        }
        #pragma unroll
        for (int r = 0; r < 4; ++r)
            lds[OFF_AVT + (dt*16 + li) * SAVT_LD + w*16 + g*4 + r] = f2bf(acc[r]);
    }
    __syncthreads();   // sK/sVt now dead; sP2 may overwrite them

    // ---- Phase 2: S2 = Q·A^T, softmax over 49 agents ----
    {
        bf16x8 ab[4];
        #pragma unroll
        for (int at = 0; at < 4; ++at)
            ab[at] = *reinterpret_cast<bf16x8*>(&lds[OFF_A + (at*16 + li) * SA_LD + g*8]);
        for (int j = w; j < 13; j += 4) {
            const int qrow = min(j*16 + li, NTOK - 1);
            bf16x8 qf = *reinterpret_cast<const bf16x8*>(
                &qb[((size_t)(b * NTOK) + qrow) * CDIM + h * HDIM + g*8]);
            f32x4 cc[4];
            #pragma unroll
            for (int at = 0; at < 4; ++at)
                cc[at] = __builtin_amdgcn_mfma_f32_16x16x32_bf16(qf, ab[at], z, 0, 0, 0);
            #pragma unroll
            for (int r = 0; r < 4; ++r) {
                float m = -1e30f;
                #pragma unroll
                for (int at = 0; at < 4; ++at)
                    if (at < 3 || li < 1) m = fmaxf(m, cc[at][r]);  // col at*16+li < 49
                #pragma unroll
                for (int d = 1; d < 16; d <<= 1) m = fmaxf(m, __shfl_xor(m, d));
                float p[4]; float su = 0.f;
                #pragma unroll
                for (int at = 0; at < 4; ++at) {
                    p[at] = (at < 3 || li < 1) ? __expf(cc[at][r] - m) : 0.f;
                    su += p[at];
                }
                #pragma unroll
                for (int d = 1; d < 16; d <<= 1) su += __shfl_xor(su, d);
                const float inv = 1.f / su;
                const int trow = j*16 + g*4 + r;
                #pragma unroll
                for (int at = 0; at < 4; ++at)
                    lds[OFF_P2 + trow * SP2_LD + at*16 + li] = f2bf(p[at] * inv);
            }
        }
    }
    __syncthreads();   // all Q reads done; sP2/sAVt visible to all waves

    // ---- Phase 3: O = P2·AV (K=64 over agents), write qb in place ----
    for (int j = w; j < 13; j += 4) {
        #pragma unroll
        for (int dt = 0; dt < 2; ++dt) {
            f32x4 acc = z;
            #pragma unroll
            for (int kk = 0; kk < 2; ++kk) {
                bf16x8 pf = *reinterpret_cast<bf16x8*>(
                    &lds[OFF_P2 + (j*16 + li) * SP2_LD + kk*32 + g*8]);
                bf16x8 avf = *reinterpret_cast<bf16x8*>(
                    &lds[OFF_AVT + (dt*16 + li) * SAVT_LD + kk*32 + g*8]);
                acc = __builtin_amdgcn_mfma_f32_16x16x32_bf16(pf, avf, acc, 0, 0, 0);
            }
            #pragma unroll
            for (int r = 0; r < 4; ++r) {
                const int t = j*16 + g*4 + r;
                if (t < NTOK)
                    qb[((size_t)(b * NTOK) + t) * CDIM + h * HDIM + dt*16 + li]
                        = f2bf(acc[r]);
            }
        }
    }
}

// ---------------------------------------------------------------------------
extern "C" void kernel_launch(void* const* d_in, const int* in_sizes, int n_in,
                              void* d_out, int out_size, void* d_ws, size_t ws_size,
                              hipStream_t stream)
{
    const float* x     = (const float*)d_in[0];
    const float* wq    = (const float*)d_in[1];
    const float* wkv   = (const float*)d_in[2];
    const float* wproj = (const float*)d_in[3];
    const float* bproj = (const float*)d_in[4];
    float* out = (float*)d_out;

    // workspace (u16 elements), total 45,219,840 u16 = 90.4 MB (same as proven)
    u16* wqb    = (u16*)d_ws;                        //     65,536
    u16* wkvb   = wqb    + 65536;                    //    131,072
    u16* wprojb = wkvb   + 131072;                   //     65,536
    u16* qb     = wprojb + 65536;                    // 25,690,112 (q -> attn out in place)
    u16* agentb = qb     + (size_t)M_ROWS * CDIM;    //  6,422,528
    u16* kvb    = agentb + (size_t)NB*ANUM*CDIM;     // 12,845,056 (chunk-reused)

    const dim3 blk(256);

    // 0) weights -> bf16
    cast_w<<<dim3(256), blk, 0, stream>>>(wq, wkv, wproj, wqb, wkvb, wprojb);
    // 1) q = x @ wq^T (bf16)
    gemm_f32a<<<dim3(M_ROWS/128, 2), blk, 0, stream>>>(x, wqb, qb, 256);
    // 2) agent pooling
    pool_kernel<<<dim3((NB*ANUM*CDIM)/256), blk, 0, stream>>>(qb, agentb);
    // 3) per-chunk: kv GEMM + fused attention (qb updated in place)
    for (int ch = 0; ch < NCHUNK; ++ch) {
        const float* xch = x + (size_t)ch * CB * NTOK * CDIM;
        gemm_f32a<<<dim3((CB*NTOK)/128, 4), blk, 0, stream>>>(xch, wkvb, kvb, 512);
        fused_attn<<<dim3(CB*NHEADS), blk, 0, stream>>>(kvb, agentb, qb, ch*CB);
    }
    // 4) out = attn @ wproj^T + bias
    gemm_bf16a<<<dim3(M_ROWS/128, 2), blk, 0, stream>>>(qb, wprojb, bproj, out, 256);
}

// Round 7
// 454.738 us; speedup vs baseline: 3.4280x; 1.1658x over previous
//
#include <hip/hip_runtime.h>

typedef unsigned short u16;
typedef __attribute__((ext_vector_type(8))) short bf16x8;
typedef __attribute__((ext_vector_type(4))) float f32x4;

// Problem dims
#define M_ROWS 100352   // 512 * 196
#define NB     512
#define NTOK   196
#define CDIM   256
#define NHEADS 8
#define HDIM   32
#define ANUM   49

__device__ __forceinline__ u16 f2bf(float f) {
    union { float f; unsigned u; } c; c.f = f;
    return (u16)((c.u + 0x7FFFu + ((c.u >> 16) & 1u)) >> 16);
}
__device__ __forceinline__ float bf2f(u16 u) {
    union { unsigned u; float f; } c; c.u = ((unsigned)u) << 16;
    return c.f;
}

// ---------------------------------------------------------------------------
// Cast x and all weights to bf16 in one pass (4 elems / thread).
// wq -> rows 0..255 of wqkvb, wkv -> rows 256..767 (contiguous append).
// ---------------------------------------------------------------------------
#define NX4 6422528
__global__ __launch_bounds__(256)
void cast_all(const float* __restrict__ x, const float* __restrict__ wq,
              const float* __restrict__ wkv, const float* __restrict__ wproj,
              u16* __restrict__ xb, u16* __restrict__ wqkvb,
              u16* __restrict__ wprojb)
{
    const int idx4 = blockIdx.x * 256 + threadIdx.x;   // 0..6,488,063
    const float* src; u16* dst; int off;
    if (idx4 < NX4)               { src = x;     dst = xb;             off = idx4; }
    else if (idx4 < NX4 + 16384)  { src = wq;    dst = wqkvb;          off = idx4 - NX4; }
    else if (idx4 < NX4 + 49152)  { src = wkv;   dst = wqkvb + 65536;  off = idx4 - NX4 - 16384; }
    else                          { src = wproj; dst = wprojb;         off = idx4 - NX4 - 49152; }
    float4 v = *reinterpret_cast<const float4*>(&src[(size_t)off * 4]);
    ushort4 o;
    o.x = f2bf(v.x); o.y = f2bf(v.y); o.z = f2bf(v.z); o.w = f2bf(v.w);
    *reinterpret_cast<ushort4*>(&dst[(size_t)off * 4]) = o;
}

// ---------------------------------------------------------------------------
// Fused q+kv MFMA GEMM.  A = xb [M][256] bf16; B = wqkvb [768][256] bf16.
// cols 0..255 -> qb [M][256]; cols 256..767 -> kvb [M][512].
// Tile 128x128, BK=32, 4 waves (2x2).  LDS rows padded to 40 u16 (80 B,
// 16B-aligned, bank phase +20/row -> <=2-way aliasing, free).
// ---------------------------------------------------------------------------
#define GLD 40
__global__ __launch_bounds__(256)
void gemm_qkv(const u16* __restrict__ xb, const u16* __restrict__ wqkvb,
              u16* __restrict__ qb, u16* __restrict__ kvb)
{
    __shared__ u16 As[128 * GLD];
    __shared__ u16 Bs[128 * GLD];

    const int tid  = threadIdx.x;
    const int lane = tid & 63, wid = tid >> 6;
    const int wm = wid >> 1, wn = wid & 1;
    const int row0 = blockIdx.x * 128;
    const int col0 = blockIdx.y * 128;

    f32x4 acc[4][4] = {};
    const int lrow = lane & 15;
    const int lk   = (lane >> 4) * 8;

    for (int k0 = 0; k0 < 256; k0 += 32) {
        #pragma unroll
        for (int i = 0; i < 2; ++i) {
            const int c = tid + i * 256;
            const int r = c >> 2, kc = c & 3;
            bf16x8 va = *reinterpret_cast<const bf16x8*>(
                &xb[(size_t)(row0 + r) * 256 + k0 + kc * 8]);
            *reinterpret_cast<bf16x8*>(&As[r * GLD + kc * 8]) = va;
            bf16x8 vb = *reinterpret_cast<const bf16x8*>(
                &wqkvb[(size_t)(col0 + r) * 256 + k0 + kc * 8]);
            *reinterpret_cast<bf16x8*>(&Bs[r * GLD + kc * 8]) = vb;
        }
        __syncthreads();

        bf16x8 af[4], bfr[4];
        #pragma unroll
        for (int m = 0; m < 4; ++m)
            af[m] = *reinterpret_cast<bf16x8*>(&As[(wm*64 + m*16 + lrow) * GLD + lk]);
        #pragma unroll
        for (int n = 0; n < 4; ++n)
            bfr[n] = *reinterpret_cast<bf16x8*>(&Bs[(wn*64 + n*16 + lrow) * GLD + lk]);
        #pragma unroll
        for (int m = 0; m < 4; ++m)
            #pragma unroll
            for (int n = 0; n < 4; ++n)
                acc[m][n] = __builtin_amdgcn_mfma_f32_16x16x32_bf16(
                                af[m], bfr[n], acc[m][n], 0, 0, 0);
        __syncthreads();
    }

    // C/D layout: col = lane&15, row = (lane>>4)*4 + r
    const bool isq = (col0 < 256);
    u16* C = isq ? qb : kvb;
    const int ldc = isq ? 256 : 512;
    const int cb  = isq ? col0 : col0 - 256;
    #pragma unroll
    for (int n = 0; n < 4; ++n) {
        const int ccol = cb + wn*64 + n*16 + (lane & 15);
        #pragma unroll
        for (int m = 0; m < 4; ++m) {
            const int rbase = row0 + wm*64 + m*16 + (lane >> 4) * 4;
            #pragma unroll
            for (int r = 0; r < 4; ++r)
                C[(size_t)(rbase + r) * ldc + ccol] = f2bf(acc[m][n][r]);
        }
    }
}

// ---------------------------------------------------------------------------
// Proj MFMA GEMM: A bf16 [M][256], B wprojb [256][256], C fp32 + bias.
// ---------------------------------------------------------------------------
__global__ __launch_bounds__(256)
void gemm_proj(const u16* __restrict__ A, const u16* __restrict__ Bw,
               const float* __restrict__ bias, float* __restrict__ C)
{
    __shared__ u16 As[128 * GLD];
    __shared__ u16 Bs[128 * GLD];

    const int tid  = threadIdx.x;
    const int lane = tid & 63, wid = tid >> 6;
    const int wm = wid >> 1, wn = wid & 1;
    const int row0 = blockIdx.x * 128;
    const int col0 = blockIdx.y * 128;

    f32x4 acc[4][4] = {};
    const int lrow = lane & 15;
    const int lk   = (lane >> 4) * 8;

    for (int k0 = 0; k0 < 256; k0 += 32) {
        #pragma unroll
        for (int i = 0; i < 2; ++i) {
            const int c = tid + i * 256;
            const int r = c >> 2, kc = c & 3;
            bf16x8 va = *reinterpret_cast<const bf16x8*>(
                &A[(size_t)(row0 + r) * 256 + k0 + kc * 8]);
            *reinterpret_cast<bf16x8*>(&As[r * GLD + kc * 8]) = va;
            bf16x8 vb = *reinterpret_cast<const bf16x8*>(
                &Bw[(size_t)(col0 + r) * 256 + k0 + kc * 8]);
            *reinterpret_cast<bf16x8*>(&Bs[r * GLD + kc * 8]) = vb;
        }
        __syncthreads();

        bf16x8 af[4], bfr[4];
        #pragma unroll
        for (int m = 0; m < 4; ++m)
            af[m] = *reinterpret_cast<bf16x8*>(&As[(wm*64 + m*16 + lrow) * GLD + lk]);
        #pragma unroll
        for (int n = 0; n < 4; ++n)
            bfr[n] = *reinterpret_cast<bf16x8*>(&Bs[(wn*64 + n*16 + lrow) * GLD + lk]);
        #pragma unroll
        for (int m = 0; m < 4; ++m)
            #pragma unroll
            for (int n = 0; n < 4; ++n)
                acc[m][n] = __builtin_amdgcn_mfma_f32_16x16x32_bf16(
                                af[m], bfr[n], acc[m][n], 0, 0, 0);
        __syncthreads();
    }

    #pragma unroll
    for (int n = 0; n < 4; ++n) {
        const int ccol = col0 + wn*64 + n*16 + (lane & 15);
        const float bv = bias[ccol];
        #pragma unroll
        for (int m = 0; m < 4; ++m) {
            const int rbase = row0 + wm*64 + m*16 + (lane >> 4) * 4;
            #pragma unroll
            for (int r = 0; r < 4; ++r)
                C[(size_t)(rbase + r) * 256 + ccol] = acc[m][n][r] + bv;
        }
    }
}

// ---------------------------------------------------------------------------
// Agent pooling over bf16 q: agent[b][a][ch] = mean of 2x2 block.
// ---------------------------------------------------------------------------
__global__ __launch_bounds__(256)
void pool_kernel(const u16* __restrict__ qb, u16* __restrict__ agentb)
{
    const int idx = blockIdx.x * 256 + threadIdx.x;
    const int ch = idx & 255;
    const int a  = (idx >> 8) % ANUM;
    const int b  = idx / (ANUM * CDIM);
    const int p1 = a / 7, p2 = a % 7;
    const u16* q0 = qb + (size_t)b * NTOK * CDIM;
    float s = 0.f;
    #pragma unroll
    for (int i2 = 0; i2 < 2; ++i2)
        #pragma unroll
        for (int j2 = 0; j2 < 2; ++j2) {
            const int n = (p1*2 + i2) * 14 + (p2*2 + j2);
            s += bf2f(q0[(size_t)n * CDIM + ch]);
        }
    agentb[idx] = f2bf(0.25f * s);
}

// ---------------------------------------------------------------------------
// Fused agent attention per (b,h): all 4 einsums via MFMA 16x16x32 (K=32=HDIM).
//   S1 = (A*scale)·K^T  -> softmax_n -> P1 ; AV = P1·V   (stored transposed)
//   S2 = Q·(A*scale)^T  -> softmax_a -> P2 ; O  = P2·AV  -> qb in place
// (identical to the round-6 kernel, now one full-size launch, b global)
// ---------------------------------------------------------------------------
#define SA_LD   40
#define SK_LD   40
#define SVT_LD  232
#define SP1_LD  232
#define SAVT_LD 72
#define SP2_LD  72
#define OFF_A   0
#define OFF_K   2560     // 64*40
#define OFF_VT  10880    // OFF_K + 208*40
#define OFF_P2  2560     // alias over sK+sVt (ends 17536 < OFF_P1)
#define OFF_P1  18304    // OFF_VT + 32*232
#define OFF_AVT 33152    // OFF_P1 + 64*232
#define LDS_U16 35456    // OFF_AVT + 32*72 (= 70,912 B)

__global__ __launch_bounds__(256)
void fused_attn(const u16* __restrict__ kvb, const u16* __restrict__ agentb,
                u16* __restrict__ qb)
{
    __shared__ __align__(16) u16 lds[LDS_U16];
    const int tid  = threadIdx.x;
    const int lane = tid & 63, w = tid >> 6;
    const int li = lane & 15, g = lane >> 4;
    const int b = blockIdx.x >> 3, h = blockIdx.x & 7;
    const float scale = 0.1767766952966369f;   // 32^-0.5
    const f32x4 z = {0.f, 0.f, 0.f, 0.f};

    // zero all of LDS (pad rows/cols must be 0)
    for (int i = tid; i < LDS_U16 / 8; i += 256)
        *reinterpret_cast<f32x4*>(&lds[i * 8]) = z;
    __syncthreads();

    // ---- stage sA (pre-scaled), sK, sVt (transposed) ----
    {
        const int a = tid >> 2, kc = tid & 3;
        if (a < ANUM) {
            bf16x8 v = *reinterpret_cast<const bf16x8*>(
                &agentb[((size_t)b * ANUM + a) * CDIM + h * HDIM + kc * 8]);
            bf16x8 t;
            #pragma unroll
            for (int j2 = 0; j2 < 8; ++j2)
                t[j2] = (short)f2bf(bf2f((u16)v[j2]) * scale);
            *reinterpret_cast<bf16x8*>(&lds[OFF_A + a * SA_LD + kc * 8]) = t;
        }
    }
    for (int i = tid; i < NTOK * 4; i += 256) {
        const int n = i >> 2, kc = i & 3;
        bf16x8 v = *reinterpret_cast<const bf16x8*>(
            &kvb[((size_t)(b * NTOK + n)) * 512 + h * HDIM + kc * 8]);
        *reinterpret_cast<bf16x8*>(&lds[OFF_K + n * SK_LD + kc * 8]) = v;
    }
    for (int i = tid; i < NTOK * 2; i += 256) {
        const int n = i >> 1, dh = i & 1;
        const u16* src = &kvb[((size_t)(b * NTOK + n)) * 512 + 256 + h * HDIM + dh * 16];
        bf16x8 v0 = *reinterpret_cast<const bf16x8*>(src);
        bf16x8 v1 = *reinterpret_cast<const bf16x8*>(src + 8);
        #pragma unroll
        for (int j2 = 0; j2 < 8; ++j2) {
            lds[OFF_VT + (dh * 16 + j2) * SVT_LD + n]     = (u16)v0[j2];
            lds[OFF_VT + (dh * 16 + 8 + j2) * SVT_LD + n] = (u16)v1[j2];
        }
    }
    __syncthreads();

    // ---- Phase 1: S1 = A·K^T (agent-tile w), softmax over 196 tokens ----
    {
        bf16x8 af = *reinterpret_cast<bf16x8*>(&lds[OFF_A + (w*16 + li) * SA_LD + g*8]);
        f32x4 c[13];
        #pragma unroll
        for (int j = 0; j < 13; ++j) {
            bf16x8 kf = *reinterpret_cast<bf16x8*>(&lds[OFF_K + (j*16 + li) * SK_LD + g*8]);
            c[j] = __builtin_amdgcn_mfma_f32_16x16x32_bf16(af, kf, z, 0, 0, 0);
        }
        #pragma unroll
        for (int r = 0; r < 4; ++r) {
            float m = -1e30f;
            #pragma unroll
            for (int j = 0; j < 13; ++j)
                if (j < 12 || li < 4) m = fmaxf(m, c[j][r]);   // col j*16+li < 196
            #pragma unroll
            for (int d = 1; d < 16; d <<= 1) m = fmaxf(m, __shfl_xor(m, d));
            float p[13]; float su = 0.f;
            #pragma unroll
            for (int j = 0; j < 13; ++j) {
                p[j] = (j < 12 || li < 4) ? __expf(c[j][r] - m) : 0.f;
                su += p[j];
            }
            #pragma unroll
            for (int d = 1; d < 16; d <<= 1) su += __shfl_xor(su, d);
            const float inv = 1.f / su;
            const int arow = w*16 + g*4 + r;
            #pragma unroll
            for (int j = 0; j < 13; ++j)
                lds[OFF_P1 + arow * SP1_LD + j*16 + li] = f2bf(p[j] * inv);
        }
    }
    __syncthreads();

    // ---- Phase 1b: AV = P1·V (K=224 over tokens), store AV^T ----
    #pragma unroll
    for (int dt = 0; dt < 2; ++dt) {
        f32x4 acc = z;
        #pragma unroll
        for (int kk = 0; kk < 7; ++kk) {
            bf16x8 pa = *reinterpret_cast<bf16x8*>(
                &lds[OFF_P1 + (w*16 + li) * SP1_LD + kk*32 + g*8]);
            bf16x8 vb = *reinterpret_cast<bf16x8*>(
                &lds[OFF_VT + (dt*16 + li) * SVT_LD + kk*32 + g*8]);
            acc = __builtin_amdgcn_mfma_f32_16x16x32_bf16(pa, vb, acc, 0, 0, 0);
        }
        #pragma unroll
        for (int r = 0; r < 4; ++r)
            lds[OFF_AVT + (dt*16 + li) * SAVT_LD + w*16 + g*4 + r] = f2bf(acc[r]);
    }
    __syncthreads();   // sK/sVt now dead; sP2 may overwrite them

    // ---- Phase 2: S2 = Q·A^T, softmax over 49 agents ----
    {
        bf16x8 ab[4];
        #pragma unroll
        for (int at = 0; at < 4; ++at)
            ab[at] = *reinterpret_cast<bf16x8*>(&lds[OFF_A + (at*16 + li) * SA_LD + g*8]);
        for (int j = w; j < 13; j += 4) {
            const int qrow = min(j*16 + li, NTOK - 1);
            bf16x8 qf = *reinterpret_cast<const bf16x8*>(
                &qb[((size_t)(b * NTOK) + qrow) * CDIM + h * HDIM + g*8]);
            f32x4 cc[4];
            #pragma unroll
            for (int at = 0; at < 4; ++at)
                cc[at] = __builtin_amdgcn_mfma_f32_16x16x32_bf16(qf, ab[at], z, 0, 0, 0);
            #pragma unroll
            for (int r = 0; r < 4; ++r) {
                float m = -1e30f;
                #pragma unroll
                for (int at = 0; at < 4; ++at)
                    if (at < 3 || li < 1) m = fmaxf(m, cc[at][r]);  // col at*16+li < 49
                #pragma unroll
                for (int d = 1; d < 16; d <<= 1) m = fmaxf(m, __shfl_xor(m, d));
                float p[4]; float su = 0.f;
                #pragma unroll
                for (int at = 0; at < 4; ++at) {
                    p[at] = (at < 3 || li < 1) ? __expf(cc[at][r] - m) : 0.f;
                    su += p[at];
                }
                #pragma unroll
                for (int d = 1; d < 16; d <<= 1) su += __shfl_xor(su, d);
                const float inv = 1.f / su;
                const int trow = j*16 + g*4 + r;
                #pragma unroll
                for (int at = 0; at < 4; ++at)
                    lds[OFF_P2 + trow * SP2_LD + at*16 + li] = f2bf(p[at] * inv);
            }
        }
    }
    __syncthreads();   // all Q reads done; sP2/sAVt visible to all waves

    // ---- Phase 3: O = P2·AV (K=64 over agents), write qb in place ----
    for (int j = w; j < 13; j += 4) {
        #pragma unroll
        for (int dt = 0; dt < 2; ++dt) {
            f32x4 acc = z;
            #pragma unroll
            for (int kk = 0; kk < 2; ++kk) {
                bf16x8 pf = *reinterpret_cast<bf16x8*>(
                    &lds[OFF_P2 + (j*16 + li) * SP2_LD + kk*32 + g*8]);
                bf16x8 avf = *reinterpret_cast<bf16x8*>(
                    &lds[OFF_AVT + (dt*16 + li) * SAVT_LD + kk*32 + g*8]);
                acc = __builtin_amdgcn_mfma_f32_16x16x32_bf16(pf, avf, acc, 0, 0, 0);
            }
            #pragma unroll
            for (int r = 0; r < 4; ++r) {
                const int t = j*16 + g*4 + r;
                if (t < NTOK)
                    qb[((size_t)(b * NTOK) + t) * CDIM + h * HDIM + dt*16 + li]
                        = f2bf(acc[r]);
            }
        }
    }
}

// ---------------------------------------------------------------------------
extern "C" void kernel_launch(void* const* d_in, const int* in_sizes, int n_in,
                              void* d_out, int out_size, void* d_ws, size_t ws_size,
                              hipStream_t stream)
{
    const float* x     = (const float*)d_in[0];
    const float* wq    = (const float*)d_in[1];
    const float* wkv   = (const float*)d_in[2];
    const float* wproj = (const float*)d_in[3];
    const float* bproj = (const float*)d_in[4];
    float* out = (float*)d_out;

    // workspace (u16 elements): total 109,445,120 u16 = 218.9 MB
    // (measured ws_size = 411,041,792 B; round-2 crash was a 512 KB overflow)
    u16* wqkvb  = (u16*)d_ws;                        //    196,608  [wq;wkv] rows
    u16* wprojb = wqkvb  + 196608;                   //     65,536
    u16* xb     = wprojb + 65536;                    // 25,690,112
    u16* qb     = xb     + (size_t)M_ROWS * CDIM;    // 25,690,112 (q -> attn out in place)
    u16* agentb = qb     + (size_t)M_ROWS * CDIM;    //  6,422,528
    u16* kvb    = agentb + (size_t)NB*ANUM*CDIM;     // 51,380,224 (full, k|v interleaved)

    const dim3 blk(256);

    // 0) x + weights -> bf16
    cast_all<<<dim3(25344), blk, 0, stream>>>(x, wq, wkv, wproj, xb, wqkvb, wprojb);
    // 1) fused q+kv GEMM: [M,256] x [768,256]^T -> qb / kvb
    gemm_qkv<<<dim3(M_ROWS/128, 6), blk, 0, stream>>>(xb, wqkvb, qb, kvb);
    // 2) agent pooling
    pool_kernel<<<dim3((NB*ANUM*CDIM)/256), blk, 0, stream>>>(qb, agentb);
    // 3) fused attention (qb updated in place), one launch
    fused_attn<<<dim3(NB*NHEADS), blk, 0, stream>>>(kvb, agentb, qb);
    // 4) out = attn @ wproj^T + bias
    gemm_proj<<<dim3(M_ROWS/128, 2), blk, 0, stream>>>(qb, wprojb, bproj, out);
}

// Round 8
// 448.480 us; speedup vs baseline: 3.4758x; 1.0140x over previous
//
#include <hip/hip_runtime.h>

typedef unsigned short u16;
typedef __attribute__((ext_vector_type(8))) short bf16x8;
typedef __attribute__((ext_vector_type(4))) float f32x4;

// Problem dims
#define M_ROWS 100352   // 512 * 196
#define NB     512
#define NTOK   196
#define CDIM   256
#define NHEADS 8
#define HDIM   32
#define ANUM   49

__device__ __forceinline__ u16 f2bf(float f) {
    union { float f; unsigned u; } c; c.f = f;
    return (u16)((c.u + 0x7FFFu + ((c.u >> 16) & 1u)) >> 16);
}
__device__ __forceinline__ float bf2f(u16 u) {
    union { unsigned u; float f; } c; c.u = ((unsigned)u) << 16;
    return c.f;
}

// ---------------------------------------------------------------------------
// Cast x and all weights to bf16 in one pass (4 elems / thread).
// wq -> rows 0..255 of wqkvb, wkv -> rows 256..767.
// ---------------------------------------------------------------------------
#define NX4 6422528
__global__ __launch_bounds__(256)
void cast_all(const float* __restrict__ x, const float* __restrict__ wq,
              const float* __restrict__ wkv, const float* __restrict__ wproj,
              u16* __restrict__ xb, u16* __restrict__ wqkvb,
              u16* __restrict__ wprojb)
{
    const int idx4 = blockIdx.x * 256 + threadIdx.x;   // 0..6,488,063
    const float* src; u16* dst; int off;
    if (idx4 < NX4)               { src = x;     dst = xb;             off = idx4; }
    else if (idx4 < NX4 + 16384)  { src = wq;    dst = wqkvb;          off = idx4 - NX4; }
    else if (idx4 < NX4 + 49152)  { src = wkv;   dst = wqkvb + 65536;  off = idx4 - NX4 - 16384; }
    else                          { src = wproj; dst = wprojb;         off = idx4 - NX4 - 49152; }
    float4 v = *reinterpret_cast<const float4*>(&src[(size_t)off * 4]);
    ushort4 o;
    o.x = f2bf(v.x); o.y = f2bf(v.y); o.z = f2bf(v.z); o.w = f2bf(v.w);
    *reinterpret_cast<ushort4*>(&dst[(size_t)off * 4]) = o;
}

// ---------------------------------------------------------------------------
// Fused q+kv MFMA GEMM.  A = xb [M][256] bf16; B = wqkvb [768][256] bf16.
// cols 0..255 -> qb [M][256]; cols 256..767 -> kvb [M][512].
// Tile 128x128, BK=32, 4 waves (2x2).  LDS rows padded to 40 u16.
// ---------------------------------------------------------------------------
#define GLD 40
__global__ __launch_bounds__(256)
void gemm_qkv(const u16* __restrict__ xb, const u16* __restrict__ wqkvb,
              u16* __restrict__ qb, u16* __restrict__ kvb)
{
    __shared__ u16 As[128 * GLD];
    __shared__ u16 Bs[128 * GLD];

    const int tid  = threadIdx.x;
    const int lane = tid & 63, wid = tid >> 6;
    const int wm = wid >> 1, wn = wid & 1;
    const int row0 = blockIdx.x * 128;
    const int col0 = blockIdx.y * 128;

    f32x4 acc[4][4] = {};
    const int lrow = lane & 15;
    const int lk   = (lane >> 4) * 8;

    for (int k0 = 0; k0 < 256; k0 += 32) {
        #pragma unroll
        for (int i = 0; i < 2; ++i) {
            const int c = tid + i * 256;
            const int r = c >> 2, kc = c & 3;
            bf16x8 va = *reinterpret_cast<const bf16x8*>(
                &xb[(size_t)(row0 + r) * 256 + k0 + kc * 8]);
            *reinterpret_cast<bf16x8*>(&As[r * GLD + kc * 8]) = va;
            bf16x8 vb = *reinterpret_cast<const bf16x8*>(
                &wqkvb[(size_t)(col0 + r) * 256 + k0 + kc * 8]);
            *reinterpret_cast<bf16x8*>(&Bs[r * GLD + kc * 8]) = vb;
        }
        __syncthreads();

        bf16x8 af[4], bfr[4];
        #pragma unroll
        for (int m = 0; m < 4; ++m)
            af[m] = *reinterpret_cast<bf16x8*>(&As[(wm*64 + m*16 + lrow) * GLD + lk]);
        #pragma unroll
        for (int n = 0; n < 4; ++n)
            bfr[n] = *reinterpret_cast<bf16x8*>(&Bs[(wn*64 + n*16 + lrow) * GLD + lk]);
        #pragma unroll
        for (int m = 0; m < 4; ++m)
            #pragma unroll
            for (int n = 0; n < 4; ++n)
                acc[m][n] = __builtin_amdgcn_mfma_f32_16x16x32_bf16(
                                af[m], bfr[n], acc[m][n], 0, 0, 0);
        __syncthreads();
    }

    // C/D layout: col = lane&15, row = (lane>>4)*4 + r
    const bool isq = (col0 < 256);
    u16* C = isq ? qb : kvb;
    const int ldc = isq ? 256 : 512;
    const int cb  = isq ? col0 : col0 - 256;
    #pragma unroll
    for (int n = 0; n < 4; ++n) {
        const int ccol = cb + wn*64 + n*16 + (lane & 15);
        #pragma unroll
        for (int m = 0; m < 4; ++m) {
            const int rbase = row0 + wm*64 + m*16 + (lane >> 4) * 4;
            #pragma unroll
            for (int r = 0; r < 4; ++r)
                C[(size_t)(rbase + r) * ldc + ccol] = f2bf(acc[m][n][r]);
        }
    }
}

// ---------------------------------------------------------------------------
// Proj MFMA GEMM: A bf16 [M][256], B wprojb [256][256], C fp32 + bias.
// ---------------------------------------------------------------------------
__global__ __launch_bounds__(256)
void gemm_proj(const u16* __restrict__ A, const u16* __restrict__ Bw,
               const float* __restrict__ bias, float* __restrict__ C)
{
    __shared__ u16 As[128 * GLD];
    __shared__ u16 Bs[128 * GLD];

    const int tid  = threadIdx.x;
    const int lane = tid & 63, wid = tid >> 6;
    const int wm = wid >> 1, wn = wid & 1;
    const int row0 = blockIdx.x * 128;
    const int col0 = blockIdx.y * 128;

    f32x4 acc[4][4] = {};
    const int lrow = lane & 15;
    const int lk   = (lane >> 4) * 8;

    for (int k0 = 0; k0 < 256; k0 += 32) {
        #pragma unroll
        for (int i = 0; i < 2; ++i) {
            const int c = tid + i * 256;
            const int r = c >> 2, kc = c & 3;
            bf16x8 va = *reinterpret_cast<const bf16x8*>(
                &A[(size_t)(row0 + r) * 256 + k0 + kc * 8]);
            *reinterpret_cast<bf16x8*>(&As[r * GLD + kc * 8]) = va;
            bf16x8 vb = *reinterpret_cast<const bf16x8*>(
                &Bw[(size_t)(col0 + r) * 256 + k0 + kc * 8]);
            *reinterpret_cast<bf16x8*>(&Bs[r * GLD + kc * 8]) = vb;
        }
        __syncthreads();

        bf16x8 af[4], bfr[4];
        #pragma unroll
        for (int m = 0; m < 4; ++m)
            af[m] = *reinterpret_cast<bf16x8*>(&As[(wm*64 + m*16 + lrow) * GLD + lk]);
        #pragma unroll
        for (int n = 0; n < 4; ++n)
            bfr[n] = *reinterpret_cast<bf16x8*>(&Bs[(wn*64 + n*16 + lrow) * GLD + lk]);
        #pragma unroll
        for (int m = 0; m < 4; ++m)
            #pragma unroll
            for (int n = 0; n < 4; ++n)
                acc[m][n] = __builtin_amdgcn_mfma_f32_16x16x32_bf16(
                                af[m], bfr[n], acc[m][n], 0, 0, 0);
        __syncthreads();
    }

    #pragma unroll
    for (int n = 0; n < 4; ++n) {
        const int ccol = col0 + wn*64 + n*16 + (lane & 15);
        const float bv = bias[ccol];
        #pragma unroll
        for (int m = 0; m < 4; ++m) {
            const int rbase = row0 + wm*64 + m*16 + (lane >> 4) * 4;
            #pragma unroll
            for (int r = 0; r < 4; ++r)
                C[(size_t)(rbase + r) * 256 + ccol] = acc[m][n][r] + bv;
        }
    }
}

// ---------------------------------------------------------------------------
// Fused agent attention per (b,h), pooling fused in, K read direct from
// global.  All 4 einsums via MFMA 16x16x32 (K=32=HDIM).
//   A(prescaled) = pool2x2(Q_h)*scale          (in-block, LDS)
//   S1 = A·K^T -> softmax_n -> P1 ; AV = P1·V  (AV stored transposed)
//   S2 = Q·A^T -> softmax_a -> P2 ; O = P2·AV  -> qb in place
// LDS 54,272 B -> 3 blocks/CU.  Strides 40/232/72 keep conflicts <=2-way.
// P2 aliases dead VT+P1 after phase 1b.  Pads zeroed explicitly (no
// full-clear barrier).  C/D layout: row=(lane>>4)*4+r, col=lane&15.
// ---------------------------------------------------------------------------
#define SA_LD   40
#define SVT_LD  232
#define SP1_LD  232
#define SAVT_LD 72
#define SP2_LD  72
#define OFF_A   0
#define OFF_VT  2560     // 64*40
#define OFF_P1  9984     // OFF_VT + 32*232
#define OFF_AVT 24832    // OFF_P1 + 64*232
#define OFF_P2  2560     // alias VT+P1 (needs 208*72=14976 <= 22272)
#define LDS_U16 27136    // OFF_AVT + 32*72  (= 54,272 B)

__global__ __launch_bounds__(256, 3)
void fused_attn(const u16* __restrict__ kvb, u16* __restrict__ qb)
{
    __shared__ __align__(16) u16 lds[LDS_U16];
    const int tid  = threadIdx.x;
    const int lane = tid & 63, w = tid >> 6;
    const int li = lane & 15, g = lane >> 4;
    const int b = blockIdx.x >> 3, h = blockIdx.x & 7;
    const float scale = 0.1767766952966369f;   // 32^-0.5
    const f32x4 z = {0.f, 0.f, 0.f, 0.f};
    const bf16x8 zv = {0,0,0,0,0,0,0,0};
    const ushort4 z4 = {0,0,0,0};

    // ---- pad zeroing (disjoint from data writes; covered by stage barrier
    //      for A, by the phase-1 barrier for VT/P1 pads) ----
    for (int i = tid; i < 60; i += 256) {          // A rows 49..63, cols 0..31
        const int row = 49 + (i >> 2), kc = i & 3;
        *reinterpret_cast<bf16x8*>(&lds[OFF_A + row * SA_LD + kc * 8]) = zv;
    }
    for (int i = tid; i < 224; i += 256) {         // VT cols 196..223
        const int row = i / 7, c4 = 196 + (i % 7) * 4;
        *reinterpret_cast<ushort4*>(&lds[OFF_VT + row * SVT_LD + c4]) = z4;
    }
    for (int i = tid; i < 128; i += 256) {         // P1 cols 208..223
        const int row = i >> 1, c = 208 + (i & 1) * 8;
        *reinterpret_cast<bf16x8*>(&lds[OFF_P1 + row * SP1_LD + c]) = zv;
    }

    // ---- fused 2x2 pooling -> A (pre-scaled); also pre-warms Q slice ----
    const u16* qslice = qb + (size_t)b * NTOK * CDIM + h * HDIM;
    for (int i = tid; i < ANUM * 8; i += 256) {    // 392 items
        const int a = i >> 3, dq = (i & 7) * 4;
        const int p1 = a / 7, p2 = a - p1 * 7;
        float s0 = 0.f, s1 = 0.f, s2 = 0.f, s3 = 0.f;
        #pragma unroll
        for (int i2 = 0; i2 < 2; ++i2)
            #pragma unroll
            for (int j2 = 0; j2 < 2; ++j2) {
                const int n = (p1*2 + i2) * 14 + p2*2 + j2;
                ushort4 v = *reinterpret_cast<const ushort4*>(
                    &qslice[(size_t)n * CDIM + dq]);
                s0 += bf2f(v.x); s1 += bf2f(v.y);
                s2 += bf2f(v.z); s3 += bf2f(v.w);
            }
        const float cc = 0.25f * scale;
        ushort4 o;
        o.x = f2bf(s0 * cc); o.y = f2bf(s1 * cc);
        o.z = f2bf(s2 * cc); o.w = f2bf(s3 * cc);
        *reinterpret_cast<ushort4*>(&lds[OFF_A + a * SA_LD + dq]) = o;
    }

    // ---- V -> VT (transposed) staging ----
    for (int i = tid; i < NTOK * 2; i += 256) {
        const int n = i >> 1, dh = i & 1;
        const u16* src = &kvb[((size_t)(b * NTOK + n)) * 512 + 256 + h * HDIM + dh * 16];
        bf16x8 v0 = *reinterpret_cast<const bf16x8*>(src);
        bf16x8 v1 = *reinterpret_cast<const bf16x8*>(src + 8);
        #pragma unroll
        for (int j2 = 0; j2 < 8; ++j2) {
            lds[OFF_VT + (dh * 16 + j2) * SVT_LD + n]     = (u16)v0[j2];
            lds[OFF_VT + (dh * 16 + 8 + j2) * SVT_LD + n] = (u16)v1[j2];
        }
    }
    __syncthreads();

    // ---- Phase 1: S1 = A·K^T (K direct from global), softmax over 196 ----
    {
        bf16x8 af = *reinterpret_cast<bf16x8*>(&lds[OFF_A + (w*16 + li) * SA_LD + g*8]);
        f32x4 c[13];
        #pragma unroll
        for (int j = 0; j < 13; ++j) {
            int krow = j*16 + li; krow = krow > 195 ? 195 : krow;
            bf16x8 kf = *reinterpret_cast<const bf16x8*>(
                &kvb[((size_t)(b * NTOK + krow)) * 512 + h * HDIM + g*8]);
            c[j] = __builtin_amdgcn_mfma_f32_16x16x32_bf16(af, kf, z, 0, 0, 0);
        }
        #pragma unroll
        for (int r = 0; r < 4; ++r) {
            float m = -1e30f;
            #pragma unroll
            for (int j = 0; j < 13; ++j)
                if (j < 12 || li < 4) m = fmaxf(m, c[j][r]);   // col j*16+li < 196
            #pragma unroll
            for (int d = 1; d < 16; d <<= 1) m = fmaxf(m, __shfl_xor(m, d));
            float p[13]; float su = 0.f;
            #pragma unroll
            for (int j = 0; j < 13; ++j) {
                p[j] = (j < 12 || li < 4) ? __expf(c[j][r] - m) : 0.f;
                su += p[j];
            }
            #pragma unroll
            for (int d = 1; d < 16; d <<= 1) su += __shfl_xor(su, d);
            const float inv = 1.f / su;
            const int arow = w*16 + g*4 + r;
            #pragma unroll
            for (int j = 0; j < 13; ++j)
                lds[OFF_P1 + arow * SP1_LD + j*16 + li] = f2bf(p[j] * inv);
        }
    }
    __syncthreads();

    // ---- Phase 1b: AV = P1·V (K=224 over tokens), store AV^T ----
    #pragma unroll
    for (int dt = 0; dt < 2; ++dt) {
        f32x4 acc = z;
        #pragma unroll
        for (int kk = 0; kk < 7; ++kk) {
            bf16x8 pa = *reinterpret_cast<bf16x8*>(
                &lds[OFF_P1 + (w*16 + li) * SP1_LD + kk*32 + g*8]);
            bf16x8 vb = *reinterpret_cast<bf16x8*>(
                &lds[OFF_VT + (dt*16 + li) * SVT_LD + kk*32 + g*8]);
            acc = __builtin_amdgcn_mfma_f32_16x16x32_bf16(pa, vb, acc, 0, 0, 0);
        }
        #pragma unroll
        for (int r = 0; r < 4; ++r)
            lds[OFF_AVT + (dt*16 + li) * SAVT_LD + w*16 + g*4 + r] = f2bf(acc[r]);
    }
    __syncthreads();   // VT+P1 now dead; P2 may overwrite them

    // ---- Phase 2: S2 = Q·A^T, softmax over 49 agents (Q is L2-hot) ----
    {
        bf16x8 ab[4];
        #pragma unroll
        for (int at = 0; at < 4; ++at)
            ab[at] = *reinterpret_cast<bf16x8*>(&lds[OFF_A + (at*16 + li) * SA_LD + g*8]);
        for (int j = w; j < 13; j += 4) {
            const int qrow = min(j*16 + li, NTOK - 1);
            bf16x8 qf = *reinterpret_cast<const bf16x8*>(
                &qb[((size_t)(b * NTOK) + qrow) * CDIM + h * HDIM + g*8]);
            f32x4 cc[4];
            #pragma unroll
            for (int at = 0; at < 4; ++at)
                cc[at] = __builtin_amdgcn_mfma_f32_16x16x32_bf16(qf, ab[at], z, 0, 0, 0);
            #pragma unroll
            for (int r = 0; r < 4; ++r) {
                float m = -1e30f;
                #pragma unroll
                for (int at = 0; at < 4; ++at)
                    if (at < 3 || li < 1) m = fmaxf(m, cc[at][r]);  // col at*16+li < 49
                #pragma unroll
                for (int d = 1; d < 16; d <<= 1) m = fmaxf(m, __shfl_xor(m, d));
                float p[4]; float su = 0.f;
                #pragma unroll
                for (int at = 0; at < 4; ++at) {
                    p[at] = (at < 3 || li < 1) ? __expf(cc[at][r] - m) : 0.f;
                    su += p[at];
                }
                #pragma unroll
                for (int d = 1; d < 16; d <<= 1) su += __shfl_xor(su, d);
                const float inv = 1.f / su;
                const int trow = j*16 + g*4 + r;
                #pragma unroll
                for (int at = 0; at < 4; ++at)
                    lds[OFF_P2 + trow * SP2_LD + at*16 + li] = f2bf(p[at] * inv);
            }
        }
    }
    __syncthreads();   // all Q reads done; P2/AVT visible

    // ---- Phase 3: O = P2·AV (K=64 over agents), write qb in place ----
    for (int j = w; j < 13; j += 4) {
        #pragma unroll
        for (int dt = 0; dt < 2; ++dt) {
            f32x4 acc = z;
            #pragma unroll
            for (int kk = 0; kk < 2; ++kk) {
                bf16x8 pf = *reinterpret_cast<bf16x8*>(
                    &lds[OFF_P2 + (j*16 + li) * SP2_LD + kk*32 + g*8]);
                bf16x8 avf = *reinterpret_cast<bf16x8*>(
                    &lds[OFF_AVT + (dt*16 + li) * SAVT_LD + kk*32 + g*8]);
                acc = __builtin_amdgcn_mfma_f32_16x16x32_bf16(pf, avf, acc, 0, 0, 0);
            }
            #pragma unroll
            for (int r = 0; r < 4; ++r) {
                const int t = j*16 + g*4 + r;
                if (t < NTOK)
                    qb[((size_t)(b * NTOK) + t) * CDIM + h * HDIM + dt*16 + li]
                        = f2bf(acc[r]);
            }
        }
    }
}

// ---------------------------------------------------------------------------
extern "C" void kernel_launch(void* const* d_in, const int* in_sizes, int n_in,
                              void* d_out, int out_size, void* d_ws, size_t ws_size,
                              hipStream_t stream)
{
    const float* x     = (const float*)d_in[0];
    const float* wq    = (const float*)d_in[1];
    const float* wkv   = (const float*)d_in[2];
    const float* wproj = (const float*)d_in[3];
    const float* bproj = (const float*)d_in[4];
    float* out = (float*)d_out;

    // workspace (u16 elements): total 103,022,592 u16 = 206 MB (< 411 MB)
    u16* wqkvb  = (u16*)d_ws;                        //    196,608
    u16* wprojb = wqkvb  + 196608;                   //     65,536
    u16* xb     = wprojb + 65536;                    // 25,690,112
    u16* qb     = xb     + (size_t)M_ROWS * CDIM;    // 25,690,112 (q -> attn out in place)
    u16* kvb    = qb     + (size_t)M_ROWS * CDIM;    // 51,380,224

    const dim3 blk(256);

    // 0) x + weights -> bf16
    cast_all<<<dim3(25344), blk, 0, stream>>>(x, wq, wkv, wproj, xb, wqkvb, wprojb);
    // 1) fused q+kv GEMM: [M,256] x [768,256]^T -> qb / kvb
    gemm_qkv<<<dim3(M_ROWS/128, 6), blk, 0, stream>>>(xb, wqkvb, qb, kvb);
    // 2) fused pooling + attention (qb updated in place)
    fused_attn<<<dim3(NB*NHEADS), blk, 0, stream>>>(kvb, qb);
    // 3) out = attn @ wproj^T + bias
    gemm_proj<<<dim3(M_ROWS/128, 2), blk, 0, stream>>>(qb, wprojb, bproj, out);
}

// Round 9
// 403.248 us; speedup vs baseline: 3.8657x; 1.1122x over previous
//
#include <hip/hip_runtime.h>

typedef unsigned short u16;
typedef __attribute__((ext_vector_type(8))) short bf16x8;
typedef __attribute__((ext_vector_type(4))) float f32x4;

// Problem dims
#define M_ROWS 100352   // 512 * 196
#define NB     512
#define NTOK   196
#define CDIM   256
#define NHEADS 8
#define HDIM   32
#define ANUM   49
#define PLSTRIDE 6272   // 196*32, one (b,h) plane

__device__ __forceinline__ u16 f2bf(float f) {
    union { float f; unsigned u; } c; c.f = f;
    return (u16)((c.u + 0x7FFFu + ((c.u >> 16) & 1u)) >> 16);
}
__device__ __forceinline__ float bf2f(u16 u) {
    union { unsigned u; float f; } c; c.u = ((unsigned)u) << 16;
    return c.f;
}

// ---------------------------------------------------------------------------
// Cast x and all weights to bf16 in one pass (4 elems / thread).
// ---------------------------------------------------------------------------
#define NX4 6422528
__global__ __launch_bounds__(256)
void cast_all(const float* __restrict__ x, const float* __restrict__ wq,
              const float* __restrict__ wkv, const float* __restrict__ wproj,
              u16* __restrict__ xb, u16* __restrict__ wqkvb,
              u16* __restrict__ wprojb)
{
    const int idx4 = blockIdx.x * 256 + threadIdx.x;   // 0..6,488,063
    const float* src; u16* dst; int off;
    if (idx4 < NX4)               { src = x;     dst = xb;             off = idx4; }
    else if (idx4 < NX4 + 16384)  { src = wq;    dst = wqkvb;          off = idx4 - NX4; }
    else if (idx4 < NX4 + 49152)  { src = wkv;   dst = wqkvb + 65536;  off = idx4 - NX4 - 16384; }
    else                          { src = wproj; dst = wprojb;         off = idx4 - NX4 - 49152; }
    float4 v = *reinterpret_cast<const float4*>(&src[(size_t)off * 4]);
    ushort4 o;
    o.x = f2bf(v.x); o.y = f2bf(v.y); o.z = f2bf(v.z); o.w = f2bf(v.w);
    *reinterpret_cast<ushort4*>(&dst[(size_t)off * 4]) = o;
}

// ---------------------------------------------------------------------------
// Fused q+kv MFMA GEMM.  A = xb [M][256] bf16; B = wqkvb [768][256] bf16.
// Output scattered HEAD-MAJOR: plane p (0=q,1=k,2=v), head hh, giving
// dst[((b*8+hh)*196+n)*32 + d]   (each (b,h) plane contiguous 12.5 KB).
// Tile 128x128, BK=32, 4 waves (2x2).  LDS rows padded to 40 u16.
// ---------------------------------------------------------------------------
#define GLD 40
__global__ __launch_bounds__(256)
void gemm_qkv(const u16* __restrict__ xb, const u16* __restrict__ wqkvb,
              u16* __restrict__ qh, u16* __restrict__ kh, u16* __restrict__ vh)
{
    __shared__ u16 As[128 * GLD];
    __shared__ u16 Bs[128 * GLD];

    const int tid  = threadIdx.x;
    const int lane = tid & 63, wid = tid >> 6;
    const int wm = wid >> 1, wn = wid & 1;
    const int row0 = blockIdx.x * 128;
    const int col0 = blockIdx.y * 128;

    f32x4 acc[4][4] = {};
    const int lrow = lane & 15;
    const int lk   = (lane >> 4) * 8;

    for (int k0 = 0; k0 < 256; k0 += 32) {
        #pragma unroll
        for (int i = 0; i < 2; ++i) {
            const int c = tid + i * 256;
            const int r = c >> 2, kc = c & 3;
            bf16x8 va = *reinterpret_cast<const bf16x8*>(
                &xb[(size_t)(row0 + r) * 256 + k0 + kc * 8]);
            *reinterpret_cast<bf16x8*>(&As[r * GLD + kc * 8]) = va;
            bf16x8 vb = *reinterpret_cast<const bf16x8*>(
                &wqkvb[(size_t)(col0 + r) * 256 + k0 + kc * 8]);
            *reinterpret_cast<bf16x8*>(&Bs[r * GLD + kc * 8]) = vb;
        }
        __syncthreads();

        bf16x8 af[4], bfr[4];
        #pragma unroll
        for (int m = 0; m < 4; ++m)
            af[m] = *reinterpret_cast<bf16x8*>(&As[(wm*64 + m*16 + lrow) * GLD + lk]);
        #pragma unroll
        for (int n = 0; n < 4; ++n)
            bfr[n] = *reinterpret_cast<bf16x8*>(&Bs[(wn*64 + n*16 + lrow) * GLD + lk]);
        #pragma unroll
        for (int m = 0; m < 4; ++m)
            #pragma unroll
            for (int n = 0; n < 4; ++n)
                acc[m][n] = __builtin_amdgcn_mfma_f32_16x16x32_bf16(
                                af[m], bfr[n], acc[m][n], 0, 0, 0);
        __syncthreads();
    }

    // C/D layout: col = lane&15, row = (lane>>4)*4 + r
    #pragma unroll
    for (int n = 0; n < 4; ++n) {
        const int ccol = col0 + wn*64 + n*16 + (lane & 15);
        const int pl = ccol >> 8;                 // 0=q 1=k 2=v
        const int hh = (ccol >> 5) & 7;
        const int d  = ccol & 31;
        u16* base = (pl == 0) ? qh : (pl == 1) ? kh : vh;
        #pragma unroll
        for (int m = 0; m < 4; ++m) {
            const int rbase = row0 + wm*64 + m*16 + (lane >> 4) * 4;
            #pragma unroll
            for (int r = 0; r < 4; ++r) {
                const unsigned row = rbase + r;
                const unsigned bb = row / 196u;
                const unsigned nn = row - bb * 196u;
                base[((size_t)(bb*8 + hh) * 196 + nn) * 32 + d] = f2bf(acc[m][n][r]);
            }
        }
    }
}

// ---------------------------------------------------------------------------
// Proj MFMA GEMM: A = attn output, HEAD-MAJOR planes (qh); k=h*32+d maps to
// plane addressing.  B wprojb [256][256], C fp32 [M][256] + bias.
// ---------------------------------------------------------------------------
__global__ __launch_bounds__(256)
void gemm_proj(const u16* __restrict__ qh, const u16* __restrict__ Bw,
               const float* __restrict__ bias, float* __restrict__ C)
{
    __shared__ u16 As[128 * GLD];
    __shared__ u16 Bs[128 * GLD];

    const int tid  = threadIdx.x;
    const int lane = tid & 63, wid = tid >> 6;
    const int wm = wid >> 1, wn = wid & 1;
    const int row0 = blockIdx.x * 128;
    const int col0 = blockIdx.y * 128;

    f32x4 acc[4][4] = {};
    const int lrow = lane & 15;
    const int lk   = (lane >> 4) * 8;

    for (int k0 = 0; k0 < 256; k0 += 32) {
        const int hh = k0 >> 5;    // head of this k-block
        #pragma unroll
        for (int i = 0; i < 2; ++i) {
            const int c = tid + i * 256;
            const int r = c >> 2, kc = c & 3;
            const unsigned row = row0 + r;
            const unsigned bb = row / 196u;
            const unsigned nn = row - bb * 196u;
            bf16x8 va = *reinterpret_cast<const bf16x8*>(
                &qh[((size_t)(bb*8 + hh) * 196 + nn) * 32 + kc * 8]);
            *reinterpret_cast<bf16x8*>(&As[r * GLD + kc * 8]) = va;
            bf16x8 vb = *reinterpret_cast<const bf16x8*>(
                &Bw[(size_t)(col0 + r) * 256 + k0 + kc * 8]);
            *reinterpret_cast<bf16x8*>(&Bs[r * GLD + kc * 8]) = vb;
        }
        __syncthreads();

        bf16x8 af[4], bfr[4];
        #pragma unroll
        for (int m = 0; m < 4; ++m)
            af[m] = *reinterpret_cast<bf16x8*>(&As[(wm*64 + m*16 + lrow) * GLD + lk]);
        #pragma unroll
        for (int n = 0; n < 4; ++n)
            bfr[n] = *reinterpret_cast<bf16x8*>(&Bs[(wn*64 + n*16 + lrow) * GLD + lk]);
        #pragma unroll
        for (int m = 0; m < 4; ++m)
            #pragma unroll
            for (int n = 0; n < 4; ++n)
                acc[m][n] = __builtin_amdgcn_mfma_f32_16x16x32_bf16(
                                af[m], bfr[n], acc[m][n], 0, 0, 0);
        __syncthreads();
    }

    #pragma unroll
    for (int n = 0; n < 4; ++n) {
        const int ccol = col0 + wn*64 + n*16 + (lane & 15);
        const float bv = bias[ccol];
        #pragma unroll
        for (int m = 0; m < 4; ++m) {
            const int rbase = row0 + wm*64 + m*16 + (lane >> 4) * 4;
            #pragma unroll
            for (int r = 0; r < 4; ++r)
                C[(size_t)(rbase + r) * 256 + ccol] = acc[m][n][r] + bv;
        }
    }
}

// ---------------------------------------------------------------------------
// Fused agent attention per (b,h), pooling fused, HEAD-MAJOR planes.
//   A(prescaled) = pool2x2(Q_h)*scale          (in-block, LDS)
//   S1 = A·K^T -> softmax_n -> P1 ; AV = P1·V  (AV stored transposed)
//   S2 = Q·A^T -> softmax_a -> P2 ; O = P2·AV  -> qh in place
// All global accesses contiguous within the block's 12.5 KB planes.
// LDS 54,272 B.  P2 aliases dead VT+P1 after phase 1b.
// C/D layout: row=(lane>>4)*4+r, col=lane&15.
// ---------------------------------------------------------------------------
#define SA_LD   40
#define SVT_LD  232
#define SP1_LD  232
#define SAVT_LD 72
#define SP2_LD  72
#define OFF_A   0
#define OFF_VT  2560     // 64*40
#define OFF_P1  9984     // OFF_VT + 32*232
#define OFF_AVT 24832    // OFF_P1 + 64*232
#define OFF_P2  2560     // alias VT+P1 (208*72=14976 <= 22272)
#define LDS_U16 27136    // 54,272 B

__global__ __launch_bounds__(256, 3)
void fused_attn(const u16* __restrict__ kh, const u16* __restrict__ vh,
                u16* __restrict__ qh)
{
    __shared__ __align__(16) u16 lds[LDS_U16];
    const int tid  = threadIdx.x;
    const int lane = tid & 63, w = tid >> 6;
    const int li = lane & 15, g = lane >> 4;
    const int bh = blockIdx.x;
    const float scale = 0.1767766952966369f;   // 32^-0.5
    const f32x4 z = {0.f, 0.f, 0.f, 0.f};
    const bf16x8 zv = {0,0,0,0,0,0,0,0};
    const ushort4 z4 = {0,0,0,0};

    const u16* ksl = kh + (size_t)bh * PLSTRIDE;
    const u16* vsl = vh + (size_t)bh * PLSTRIDE;
    u16*       qsl = qh + (size_t)bh * PLSTRIDE;

    // ---- pad zeroing ----
    for (int i = tid; i < 60; i += 256) {          // A rows 49..63
        const int row = 49 + (i >> 2), kc = i & 3;
        *reinterpret_cast<bf16x8*>(&lds[OFF_A + row * SA_LD + kc * 8]) = zv;
    }
    for (int i = tid; i < 224; i += 256) {         // VT cols 196..223
        const int row = i / 7, c4 = 196 + (i % 7) * 4;
        *reinterpret_cast<ushort4*>(&lds[OFF_VT + row * SVT_LD + c4]) = z4;
    }
    for (int i = tid; i < 128; i += 256) {         // P1 cols 208..223
        const int row = i >> 1, c = 208 + (i & 1) * 8;
        *reinterpret_cast<bf16x8*>(&lds[OFF_P1 + row * SP1_LD + c]) = zv;
    }

    // ---- fused 2x2 pooling -> A (pre-scaled); pre-warms Q plane ----
    for (int i = tid; i < ANUM * 8; i += 256) {    // 392 items
        const int a = i >> 3, dq = (i & 7) * 4;
        const int p1 = a / 7, p2 = a - p1 * 7;
        float s0 = 0.f, s1 = 0.f, s2 = 0.f, s3 = 0.f;
        #pragma unroll
        for (int i2 = 0; i2 < 2; ++i2)
            #pragma unroll
            for (int j2 = 0; j2 < 2; ++j2) {
                const int n = (p1*2 + i2) * 14 + p2*2 + j2;
                ushort4 v = *reinterpret_cast<const ushort4*>(&qsl[n * 32 + dq]);
                s0 += bf2f(v.x); s1 += bf2f(v.y);
                s2 += bf2f(v.z); s3 += bf2f(v.w);
            }
        const float cc = 0.25f * scale;
        ushort4 o;
        o.x = f2bf(s0 * cc); o.y = f2bf(s1 * cc);
        o.z = f2bf(s2 * cc); o.w = f2bf(s3 * cc);
        *reinterpret_cast<ushort4*>(&lds[OFF_A + a * SA_LD + dq]) = o;
    }

    // ---- V -> VT (transposed) staging; contiguous global reads ----
    for (int i = tid; i < NTOK * 4; i += 256) {    // 784 chunks of 8
        const int n = i >> 2, dc = i & 3;
        bf16x8 v = *reinterpret_cast<const bf16x8*>(&vsl[i * 8]);
        #pragma unroll
        for (int j2 = 0; j2 < 8; ++j2)
            lds[OFF_VT + (dc * 8 + j2) * SVT_LD + n] = (u16)v[j2];
    }
    __syncthreads();

    // ---- Phase 1: S1 = A·K^T (K direct from global), softmax over 196 ----
    {
        bf16x8 af = *reinterpret_cast<bf16x8*>(&lds[OFF_A + (w*16 + li) * SA_LD + g*8]);
        f32x4 c[13];
        #pragma unroll
        for (int j = 0; j < 13; ++j) {
            int krow = j*16 + li; krow = krow > 195 ? 195 : krow;
            bf16x8 kf = *reinterpret_cast<const bf16x8*>(&ksl[krow * 32 + g*8]);
            c[j] = __builtin_amdgcn_mfma_f32_16x16x32_bf16(af, kf, z, 0, 0, 0);
        }
        #pragma unroll
        for (int r = 0; r < 4; ++r) {
            float m = -1e30f;
            #pragma unroll
            for (int j = 0; j < 13; ++j)
                if (j < 12 || li < 4) m = fmaxf(m, c[j][r]);   // col j*16+li < 196
            #pragma unroll
            for (int d = 1; d < 16; d <<= 1) m = fmaxf(m, __shfl_xor(m, d));
            float p[13]; float su = 0.f;
            #pragma unroll
            for (int j = 0; j < 13; ++j) {
                p[j] = (j < 12 || li < 4) ? __expf(c[j][r] - m) : 0.f;
                su += p[j];
            }
            #pragma unroll
            for (int d = 1; d < 16; d <<= 1) su += __shfl_xor(su, d);
            const float inv = 1.f / su;
            const int arow = w*16 + g*4 + r;
            #pragma unroll
            for (int j = 0; j < 13; ++j)
                lds[OFF_P1 + arow * SP1_LD + j*16 + li] = f2bf(p[j] * inv);
        }
    }
    __syncthreads();

    // ---- Phase 1b: AV = P1·V (K=224 over tokens), store AV^T ----
    #pragma unroll
    for (int dt = 0; dt < 2; ++dt) {
        f32x4 acc = z;
        #pragma unroll
        for (int kk = 0; kk < 7; ++kk) {
            bf16x8 pa = *reinterpret_cast<bf16x8*>(
                &lds[OFF_P1 + (w*16 + li) * SP1_LD + kk*32 + g*8]);
            bf16x8 vb = *reinterpret_cast<bf16x8*>(
                &lds[OFF_VT + (dt*16 + li) * SVT_LD + kk*32 + g*8]);
            acc = __builtin_amdgcn_mfma_f32_16x16x32_bf16(pa, vb, acc, 0, 0, 0);
        }
        #pragma unroll
        for (int r = 0; r < 4; ++r)
            lds[OFF_AVT + (dt*16 + li) * SAVT_LD + w*16 + g*4 + r] = f2bf(acc[r]);
    }
    __syncthreads();   // VT+P1 now dead; P2 may overwrite

    // ---- Phase 2: S2 = Q·A^T, softmax over 49 agents ----
    {
        bf16x8 ab[4];
        #pragma unroll
        for (int at = 0; at < 4; ++at)
            ab[at] = *reinterpret_cast<bf16x8*>(&lds[OFF_A + (at*16 + li) * SA_LD + g*8]);
        for (int j = w; j < 13; j += 4) {
            const int qrow = min(j*16 + li, NTOK - 1);
            bf16x8 qf = *reinterpret_cast<const bf16x8*>(&qsl[qrow * 32 + g*8]);
            f32x4 cc[4];
            #pragma unroll
            for (int at = 0; at < 4; ++at)
                cc[at] = __builtin_amdgcn_mfma_f32_16x16x32_bf16(qf, ab[at], z, 0, 0, 0);
            #pragma unroll
            for (int r = 0; r < 4; ++r) {
                float m = -1e30f;
                #pragma unroll
                for (int at = 0; at < 4; ++at)
                    if (at < 3 || li < 1) m = fmaxf(m, cc[at][r]);  // col at*16+li < 49
                #pragma unroll
                for (int d = 1; d < 16; d <<= 1) m = fmaxf(m, __shfl_xor(m, d));
                float p[4]; float su = 0.f;
                #pragma unroll
                for (int at = 0; at < 4; ++at) {
                    p[at] = (at < 3 || li < 1) ? __expf(cc[at][r] - m) : 0.f;
                    su += p[at];
                }
                #pragma unroll
                for (int d = 1; d < 16; d <<= 1) su += __shfl_xor(su, d);
                const float inv = 1.f / su;
                const int trow = j*16 + g*4 + r;
                #pragma unroll
                for (int at = 0; at < 4; ++at)
                    lds[OFF_P2 + trow * SP2_LD + at*16 + li] = f2bf(p[at] * inv);
            }
        }
    }
    __syncthreads();   // all Q reads done; P2/AVT visible

    // ---- Phase 3: O = P2·AV (K=64 over agents), write qh in place ----
    for (int j = w; j < 13; j += 4) {
        #pragma unroll
        for (int dt = 0; dt < 2; ++dt) {
            f32x4 acc = z;
            #pragma unroll
            for (int kk = 0; kk < 2; ++kk) {
                bf16x8 pf = *reinterpret_cast<bf16x8*>(
                    &lds[OFF_P2 + (j*16 + li) * SP2_LD + kk*32 + g*8]);
                bf16x8 avf = *reinterpret_cast<bf16x8*>(
                    &lds[OFF_AVT + (dt*16 + li) * SAVT_LD + kk*32 + g*8]);
                acc = __builtin_amdgcn_mfma_f32_16x16x32_bf16(pf, avf, acc, 0, 0, 0);
            }
            #pragma unroll
            for (int r = 0; r < 4; ++r) {
                const int t = j*16 + g*4 + r;
                if (t < NTOK)
                    qsl[t * 32 + dt*16 + li] = f2bf(acc[r]);
            }
        }
    }
}

// ---------------------------------------------------------------------------
extern "C" void kernel_launch(void* const* d_in, const int* in_sizes, int n_in,
                              void* d_out, int out_size, void* d_ws, size_t ws_size,
                              hipStream_t stream)
{
    const float* x     = (const float*)d_in[0];
    const float* wq    = (const float*)d_in[1];
    const float* wkv   = (const float*)d_in[2];
    const float* wproj = (const float*)d_in[3];
    const float* bproj = (const float*)d_in[4];
    float* out = (float*)d_out;

    // workspace (u16 elements): total 103,022,592 u16 = 206 MB (< 411 MB)
    u16* wqkvb  = (u16*)d_ws;                        //    196,608
    u16* wprojb = wqkvb  + 196608;                   //     65,536
    u16* xb     = wprojb + 65536;                    // 25,690,112
    u16* qh     = xb     + (size_t)M_ROWS * CDIM;    // 25,690,112 [b][h][196][32]
    u16* kh     = qh     + (size_t)M_ROWS * CDIM;    // 25,690,112
    u16* vh     = kh     + (size_t)M_ROWS * CDIM;    // 25,690,112

    const dim3 blk(256);

    // 0) x + weights -> bf16
    cast_all<<<dim3(25344), blk, 0, stream>>>(x, wq, wkv, wproj, xb, wqkvb, wprojb);
    // 1) fused q+kv GEMM -> head-major planes
    gemm_qkv<<<dim3(M_ROWS/128, 6), blk, 0, stream>>>(xb, wqkvb, qh, kh, vh);
    // 2) fused pooling + attention (qh updated in place)
    fused_attn<<<dim3(NB*NHEADS), blk, 0, stream>>>(kh, vh, qh);
    // 3) out = attn @ wproj^T + bias
    gemm_proj<<<dim3(M_ROWS/128, 2), blk, 0, stream>>>(qh, wprojb, bproj, out);
}

// Round 10
// 385.714 us; speedup vs baseline: 4.0414x; 1.0455x over previous
//
#include <hip/hip_runtime.h>

typedef unsigned short u16;
typedef __attribute__((ext_vector_type(8))) short bf16x8;
typedef __attribute__((ext_vector_type(4))) float f32x4;

// Problem dims
#define M_ROWS 100352   // 512 * 196
#define NB     512
#define NTOK   196
#define CDIM   256
#define NHEADS 8
#define HDIM   32
#define ANUM   49
#define PLSTRIDE 6272   // 196*32, one (b,h) plane

__device__ __forceinline__ u16 f2bf(float f) {
    union { float f; unsigned u; } c; c.f = f;
    return (u16)((c.u + 0x7FFFu + ((c.u >> 16) & 1u)) >> 16);
}
__device__ __forceinline__ float bf2f(u16 u) {
    union { unsigned u; float f; } c; c.u = ((unsigned)u) << 16;
    return c.f;
}
__device__ __forceinline__ unsigned pack2(float a, float b) {
    return (unsigned)f2bf(a) | ((unsigned)f2bf(b) << 16);
}
// async global->LDS, 16B per lane; lds dest must be wave-uniform base
__device__ __forceinline__ void gload16(const void* g, void* l) {
    __builtin_amdgcn_global_load_lds(
        (const __attribute__((address_space(1))) void*)g,
        (__attribute__((address_space(3))) void*)l, 16, 0, 0);
}

// ---------------------------------------------------------------------------
// Cast x and all weights to bf16 in one pass (4 elems / thread).
// ---------------------------------------------------------------------------
#define NX4 6422528
__global__ __launch_bounds__(256)
void cast_all(const float* __restrict__ x, const float* __restrict__ wq,
              const float* __restrict__ wkv, const float* __restrict__ wproj,
              u16* __restrict__ xb, u16* __restrict__ wqkvb,
              u16* __restrict__ wprojb)
{
    const int idx4 = blockIdx.x * 256 + threadIdx.x;   // 0..6,488,063
    const float* src; u16* dst; int off;
    if (idx4 < NX4)               { src = x;     dst = xb;             off = idx4; }
    else if (idx4 < NX4 + 16384)  { src = wq;    dst = wqkvb;          off = idx4 - NX4; }
    else if (idx4 < NX4 + 49152)  { src = wkv;   dst = wqkvb + 65536;  off = idx4 - NX4 - 16384; }
    else                          { src = wproj; dst = wprojb;         off = idx4 - NX4 - 49152; }
    float4 v = *reinterpret_cast<const float4*>(&src[(size_t)off * 4]);
    ushort4 o;
    o.x = f2bf(v.x); o.y = f2bf(v.y); o.z = f2bf(v.z); o.w = f2bf(v.w);
    *reinterpret_cast<ushort4*>(&dst[(size_t)off * 4]) = o;
}

// ---------------------------------------------------------------------------
// Fused q+kv MFMA GEMM.  A = xb [M][256]; B = wqkvb [768][256].
// global_load_lds(16) staging into LINEAR [128][32] LDS (m97 structure).
// Output scattered head-major: dst[((b*8+hh)*196+n)*32 + d].
// ---------------------------------------------------------------------------
__global__ __launch_bounds__(256)
void gemm_qkv(const u16* __restrict__ xb, const u16* __restrict__ wqkvb,
              u16* __restrict__ qh, u16* __restrict__ kh, u16* __restrict__ vh)
{
    __shared__ __align__(16) u16 As[128 * 32];
    __shared__ __align__(16) u16 Bs[128 * 32];

    const int tid  = threadIdx.x;
    const int lane = tid & 63, wid = tid >> 6;
    const int wm = wid >> 1, wn = wid & 1;
    const int row0 = blockIdx.x * 128;
    const int col0 = blockIdx.y * 128;

    f32x4 acc[4][4] = {};
    const int lrow = lane & 15;
    const int lk   = (lane >> 4) * 8;

    for (int k0 = 0; k0 < 256; k0 += 32) {
        // wave wid stages 16-row chunks {wid, wid+4} of As and Bs
        for (int c = wid; c < 8; c += 4) {
            const int r = c * 16 + (lane >> 2), q = lane & 3;
            gload16(&xb[(size_t)(row0 + r) * 256 + k0 + q * 8], &As[c * 512]);
            gload16(&wqkvb[(size_t)(col0 + r) * 256 + k0 + q * 8], &Bs[c * 512]);
        }
        __syncthreads();

        bf16x8 af[4], bfr[4];
        #pragma unroll
        for (int m = 0; m < 4; ++m)
            af[m] = *reinterpret_cast<bf16x8*>(&As[(wm*64 + m*16 + lrow) * 32 + lk]);
        #pragma unroll
        for (int n = 0; n < 4; ++n)
            bfr[n] = *reinterpret_cast<bf16x8*>(&Bs[(wn*64 + n*16 + lrow) * 32 + lk]);
        #pragma unroll
        for (int m = 0; m < 4; ++m)
            #pragma unroll
            for (int n = 0; n < 4; ++n)
                acc[m][n] = __builtin_amdgcn_mfma_f32_16x16x32_bf16(
                                af[m], bfr[n], acc[m][n], 0, 0, 0);
        __syncthreads();
    }

    // C/D layout: col = lane&15, row = (lane>>4)*4 + r
    #pragma unroll
    for (int n = 0; n < 4; ++n) {
        const int ccol = col0 + wn*64 + n*16 + (lane & 15);
        const int pl = ccol >> 8;                 // 0=q 1=k 2=v
        const int hh = (ccol >> 5) & 7;
        const int d  = ccol & 31;
        u16* base = (pl == 0) ? qh : (pl == 1) ? kh : vh;
        #pragma unroll
        for (int m = 0; m < 4; ++m) {
            const int rbase = row0 + wm*64 + m*16 + (lane >> 4) * 4;
            #pragma unroll
            for (int r = 0; r < 4; ++r) {
                const unsigned row = rbase + r;
                const unsigned bb = row / 196u;
                const unsigned nn = row - bb * 196u;
                base[((size_t)(bb*8 + hh) * 196 + nn) * 32 + d] = f2bf(acc[m][n][r]);
            }
        }
    }
}

// ---------------------------------------------------------------------------
// Proj MFMA GEMM: A = head-major planes (qh), B wprojb, C fp32 + bias.
// global_load_lds(16) staging, linear LDS.
// ---------------------------------------------------------------------------
__global__ __launch_bounds__(256)
void gemm_proj(const u16* __restrict__ qh, const u16* __restrict__ Bw,
               const float* __restrict__ bias, float* __restrict__ C)
{
    __shared__ __align__(16) u16 As[128 * 32];
    __shared__ __align__(16) u16 Bs[128 * 32];

    const int tid  = threadIdx.x;
    const int lane = tid & 63, wid = tid >> 6;
    const int wm = wid >> 1, wn = wid & 1;
    const int row0 = blockIdx.x * 128;
    const int col0 = blockIdx.y * 128;

    f32x4 acc[4][4] = {};
    const int lrow = lane & 15;
    const int lk   = (lane >> 4) * 8;

    for (int k0 = 0; k0 < 256; k0 += 32) {
        const int hh = k0 >> 5;    // head of this k-block
        for (int c = wid; c < 8; c += 4) {
            const int r = c * 16 + (lane >> 2), q = lane & 3;
            const unsigned row = row0 + r;
            const unsigned bb = row / 196u;
            const unsigned nn = row - bb * 196u;
            gload16(&qh[((size_t)(bb*8 + hh) * 196 + nn) * 32 + q * 8], &As[c * 512]);
            gload16(&Bw[(size_t)(col0 + r) * 256 + k0 + q * 8], &Bs[c * 512]);
        }
        __syncthreads();

        bf16x8 af[4], bfr[4];
        #pragma unroll
        for (int m = 0; m < 4; ++m)
            af[m] = *reinterpret_cast<bf16x8*>(&As[(wm*64 + m*16 + lrow) * 32 + lk]);
        #pragma unroll
        for (int n = 0; n < 4; ++n)
            bfr[n] = *reinterpret_cast<bf16x8*>(&Bs[(wn*64 + n*16 + lrow) * 32 + lk]);
        #pragma unroll
        for (int m = 0; m < 4; ++m)
            #pragma unroll
            for (int n = 0; n < 4; ++n)
                acc[m][n] = __builtin_amdgcn_mfma_f32_16x16x32_bf16(
                                af[m], bfr[n], acc[m][n], 0, 0, 0);
        __syncthreads();
    }

    #pragma unroll
    for (int n = 0; n < 4; ++n) {
        const int ccol = col0 + wn*64 + n*16 + (lane & 15);
        const float bv = bias[ccol];
        #pragma unroll
        for (int m = 0; m < 4; ++m) {
            const int rbase = row0 + wm*64 + m*16 + (lane >> 4) * 4;
            #pragma unroll
            for (int r = 0; r < 4; ++r)
                C[(size_t)(rbase + r) * 256 + ccol] = acc[m][n][r] + bv;
        }
    }
}

// ---------------------------------------------------------------------------
// Fused agent attention per (b,h), pooling fused, head-major planes.
// SWAPPED-operand MFMA softmax phases: S1^T = mfma(K, A), S2^T = mfma(A, Q)
// so each lane holds 4 consecutive tokens/agents -> packed b64 P-stores and
// 2-shfl reductions.  Consumer layouts unchanged:
//   P1 [agent64][token 224+8pad], P2 [token][agent 64+8pad], AVT [d32][agent 64+8pad]
// ---------------------------------------------------------------------------
#define SA_LD   40
#define SVT_LD  232
#define SP1_LD  232
#define SAVT_LD 72
#define SP2_LD  72
#define OFF_A   0
#define OFF_VT  2560     // 64*40
#define OFF_P1  9984     // OFF_VT + 32*232
#define OFF_AVT 24832    // OFF_P1 + 64*232
#define OFF_P2  2560     // alias VT+P1 (196*72=14112 fits in 22272)
#define LDS_U16 27136    // 54,272 B

__global__ __launch_bounds__(256, 3)
void fused_attn(const u16* __restrict__ kh, const u16* __restrict__ vh,
                u16* __restrict__ qh)
{
    __shared__ __align__(16) u16 lds[LDS_U16];
    const int tid  = threadIdx.x;
    const int lane = tid & 63, w = tid >> 6;
    const int li = lane & 15, g = lane >> 4;
    const int bh = blockIdx.x;
    const float scale = 0.1767766952966369f;   // 32^-0.5
    const f32x4 z = {0.f, 0.f, 0.f, 0.f};
    const bf16x8 zv = {0,0,0,0,0,0,0,0};
    const ushort4 z4 = {0,0,0,0};

    const u16* ksl = kh + (size_t)bh * PLSTRIDE;
    const u16* vsl = vh + (size_t)bh * PLSTRIDE;
    u16*       qsl = qh + (size_t)bh * PLSTRIDE;

    // ---- pad zeroing ----
    for (int i = tid; i < 60; i += 256) {          // A rows 49..63
        const int row = 49 + (i >> 2), kc = i & 3;
        *reinterpret_cast<bf16x8*>(&lds[OFF_A + row * SA_LD + kc * 8]) = zv;
    }
    for (int i = tid; i < 224; i += 256) {         // VT cols 196..223
        const int row = i / 7, c4 = 196 + (i % 7) * 4;
        *reinterpret_cast<ushort4*>(&lds[OFF_VT + row * SVT_LD + c4]) = z4;
    }
    for (int i = tid; i < 128; i += 256) {         // P1 cols 208..223
        const int row = i >> 1, c = 208 + (i & 1) * 8;
        *reinterpret_cast<bf16x8*>(&lds[OFF_P1 + row * SP1_LD + c]) = zv;
    }

    // ---- fused 2x2 pooling -> A (pre-scaled); pre-warms Q plane ----
    for (int i = tid; i < ANUM * 8; i += 256) {    // 392 items
        const int a = i >> 3, dq = (i & 7) * 4;
        const int p1 = a / 7, p2 = a - p1 * 7;
        float s0 = 0.f, s1 = 0.f, s2 = 0.f, s3 = 0.f;
        #pragma unroll
        for (int i2 = 0; i2 < 2; ++i2)
            #pragma unroll
            for (int j2 = 0; j2 < 2; ++j2) {
                const int n = (p1*2 + i2) * 14 + p2*2 + j2;
                ushort4 v = *reinterpret_cast<const ushort4*>(&qsl[n * 32 + dq]);
                s0 += bf2f(v.x); s1 += bf2f(v.y);
                s2 += bf2f(v.z); s3 += bf2f(v.w);
            }
        const float cc = 0.25f * scale;
        ushort4 o;
        o.x = f2bf(s0 * cc); o.y = f2bf(s1 * cc);
        o.z = f2bf(s2 * cc); o.w = f2bf(s3 * cc);
        *reinterpret_cast<ushort4*>(&lds[OFF_A + a * SA_LD + dq]) = o;
    }

    // ---- V -> VT (transposed) staging ----
    for (int i = tid; i < NTOK * 4; i += 256) {    // 784 chunks of 8
        const int n = i >> 2, dc = i & 3;
        bf16x8 v = *reinterpret_cast<const bf16x8*>(&vsl[i * 8]);
        #pragma unroll
        for (int j2 = 0; j2 < 8; ++j2)
            lds[OFF_VT + (dc * 8 + j2) * SVT_LD + n] = (u16)v[j2];
    }
    __syncthreads();

    // ---- Phase 1: S1^T = mfma(K_j, A_w); lane holds tokens j*16+g*4+r for
    //      agent w*16+li.  Softmax over tokens = in-thread(52) + shfl 16,32.
    {
        bf16x8 af = *reinterpret_cast<bf16x8*>(&lds[OFF_A + (w*16 + li) * SA_LD + g*8]);
        f32x4 c[13];
        #pragma unroll
        for (int j = 0; j < 13; ++j) {
            int krow = j*16 + li; krow = krow > 195 ? 195 : krow;
            bf16x8 kf = *reinterpret_cast<const bf16x8*>(&ksl[krow * 32 + g*8]);
            c[j] = __builtin_amdgcn_mfma_f32_16x16x32_bf16(kf, af, z, 0, 0, 0);
        }
        float m = -1e30f;
        #pragma unroll
        for (int j = 0; j < 13; ++j)
            #pragma unroll
            for (int r = 0; r < 4; ++r)
                m = (j < 12 || g == 0) ? fmaxf(m, c[j][r]) : m;  // token < 196
        m = fmaxf(m, __shfl_xor(m, 16));
        m = fmaxf(m, __shfl_xor(m, 32));
        float su = 0.f;
        #pragma unroll
        for (int j = 0; j < 13; ++j)
            #pragma unroll
            for (int r = 0; r < 4; ++r) {
                const float p = (j < 12 || g == 0) ? __expf(c[j][r] - m) : 0.f;
                c[j][r] = p; su += p;
            }
        su += __shfl_xor(su, 16);
        su += __shfl_xor(su, 32);
        const float inv = 1.f / su;
        const int pbase = OFF_P1 + (w*16 + li) * SP1_LD + g*4;
        #pragma unroll
        for (int j = 0; j < 13; ++j) {
            uint2 pk;
            pk.x = pack2(c[j][0] * inv, c[j][1] * inv);
            pk.y = pack2(c[j][2] * inv, c[j][3] * inv);
            *reinterpret_cast<uint2*>(&lds[pbase + j*16]) = pk;
        }
    }
    __syncthreads();

    // ---- Phase 1b: AV = P1·V (K=224), store AV^T packed ----
    #pragma unroll
    for (int dt = 0; dt < 2; ++dt) {
        f32x4 acc = z;
        #pragma unroll
        for (int kk = 0; kk < 7; ++kk) {
            bf16x8 pa = *reinterpret_cast<bf16x8*>(
                &lds[OFF_P1 + (w*16 + li) * SP1_LD + kk*32 + g*8]);
            bf16x8 vb = *reinterpret_cast<bf16x8*>(
                &lds[OFF_VT + (dt*16 + li) * SVT_LD + kk*32 + g*8]);
            acc = __builtin_amdgcn_mfma_f32_16x16x32_bf16(pa, vb, acc, 0, 0, 0);
        }
        uint2 pk;
        pk.x = pack2(acc[0], acc[1]);
        pk.y = pack2(acc[2], acc[3]);
        *reinterpret_cast<uint2*>(
            &lds[OFF_AVT + (dt*16 + li) * SAVT_LD + w*16 + g*4]) = pk;
    }
    __syncthreads();   // VT+P1 now dead; P2 may overwrite

    // ---- Phase 2: S2^T = mfma(A_at, Q_j); lane holds agents at*16+g*4+r for
    //      token j*16+li.  Softmax over agents = in-thread(16) + shfl 16,32.
    {
        bf16x8 ab[4];
        #pragma unroll
        for (int at = 0; at < 4; ++at)
            ab[at] = *reinterpret_cast<bf16x8*>(&lds[OFF_A + (at*16 + li) * SA_LD + g*8]);
        for (int j = w; j < 13; j += 4) {
            const int qrow = min(j*16 + li, NTOK - 1);
            bf16x8 qf = *reinterpret_cast<const bf16x8*>(&qsl[qrow * 32 + g*8]);
            f32x4 cc[4];
            #pragma unroll
            for (int at = 0; at < 4; ++at)
                cc[at] = __builtin_amdgcn_mfma_f32_16x16x32_bf16(ab[at], qf, z, 0, 0, 0);
            float m = -1e30f;
            #pragma unroll
            for (int at = 0; at < 4; ++at)
                #pragma unroll
                for (int r = 0; r < 4; ++r)
                    m = (at < 3 || (g == 0 && r == 0)) ? fmaxf(m, cc[at][r]) : m;
            m = fmaxf(m, __shfl_xor(m, 16));
            m = fmaxf(m, __shfl_xor(m, 32));
            float su = 0.f;
            #pragma unroll
            for (int at = 0; at < 4; ++at)
                #pragma unroll
                for (int r = 0; r < 4; ++r) {
                    const float p = (at < 3 || (g == 0 && r == 0))
                                        ? __expf(cc[at][r] - m) : 0.f;
                    cc[at][r] = p; su += p;
                }
            su += __shfl_xor(su, 16);
            su += __shfl_xor(su, 32);
            const float inv = 1.f / su;
            if (j < 12 || li < 4) {               // token j*16+li valid
                const int pbase = OFF_P2 + (j*16 + li) * SP2_LD + g*4;
                #pragma unroll
                for (int at = 0; at < 4; ++at) {
                    uint2 pk;
                    pk.x = pack2(cc[at][0] * inv, cc[at][1] * inv);
                    pk.y = pack2(cc[at][2] * inv, cc[at][3] * inv);
                    *reinterpret_cast<uint2*>(&lds[pbase + at*16]) = pk;
                }
            }
        }
    }
    __syncthreads();   // P2/AVT visible

    // ---- Phase 3: O = P2·AV (K=64 over agents), write qh in place ----
    for (int j = w; j < 13; j += 4) {
        #pragma unroll
        for (int dt = 0; dt < 2; ++dt) {
            f32x4 acc = z;
            #pragma unroll
            for (int kk = 0; kk < 2; ++kk) {
                bf16x8 pf = *reinterpret_cast<bf16x8*>(
                    &lds[OFF_P2 + (j*16 + li) * SP2_LD + kk*32 + g*8]);
                bf16x8 avf = *reinterpret_cast<bf16x8*>(
                    &lds[OFF_AVT + (dt*16 + li) * SAVT_LD + kk*32 + g*8]);
                acc = __builtin_amdgcn_mfma_f32_16x16x32_bf16(pf, avf, acc, 0, 0, 0);
            }
            #pragma unroll
            for (int r = 0; r < 4; ++r) {
                const int t = j*16 + g*4 + r;
                if (t < NTOK)
                    qsl[t * 32 + dt*16 + li] = f2bf(acc[r]);
            }
        }
    }
}

// ---------------------------------------------------------------------------
extern "C" void kernel_launch(void* const* d_in, const int* in_sizes, int n_in,
                              void* d_out, int out_size, void* d_ws, size_t ws_size,
                              hipStream_t stream)
{
    const float* x     = (const float*)d_in[0];
    const float* wq    = (const float*)d_in[1];
    const float* wkv   = (const float*)d_in[2];
    const float* wproj = (const float*)d_in[3];
    const float* bproj = (const float*)d_in[4];
    float* out = (float*)d_out;

    // workspace (u16 elements): total 103,022,592 u16 = 206 MB (< 411 MB)
    u16* wqkvb  = (u16*)d_ws;                        //    196,608
    u16* wprojb = wqkvb  + 196608;                   //     65,536
    u16* xb     = wprojb + 65536;                    // 25,690,112
    u16* qh     = xb     + (size_t)M_ROWS * CDIM;    // 25,690,112 [b][h][196][32]
    u16* kh     = qh     + (size_t)M_ROWS * CDIM;    // 25,690,112
    u16* vh     = kh     + (size_t)M_ROWS * CDIM;    // 25,690,112

    const dim3 blk(256);

    // 0) x + weights -> bf16
    cast_all<<<dim3(25344), blk, 0, stream>>>(x, wq, wkv, wproj, xb, wqkvb, wprojb);
    // 1) fused q+kv GEMM -> head-major planes
    gemm_qkv<<<dim3(M_ROWS/128, 6), blk, 0, stream>>>(xb, wqkvb, qh, kh, vh);
    // 2) fused pooling + attention (qh updated in place)
    fused_attn<<<dim3(NB*NHEADS), blk, 0, stream>>>(kh, vh, qh);
    // 3) out = attn @ wproj^T + bias
    gemm_proj<<<dim3(M_ROWS/128, 2), blk, 0, stream>>>(qh, wprojb, bproj, out);
}